// Round 8
// baseline (257.103 us; speedup 1.0000x reference)
//
#include <hip/hip_runtime.h>
#include <math.h>

#define B_ 32
#define P_ 2048
#define N_ 65536
#define K_ 16
#define L_ 8
#define F_ 64
#define KS_ 5
#define KS3_ 125
#define NC_ 40
#define H_ 256
#define EPS_ 1e-5f
#define QPB_ 64
#define SEGLEN_ 256

// exact same fp expression everywhere (pinned fmaf order)
__device__ __forceinline__ float distf(float4 C, float nx, float ny, float nz, float qs) {
    return fmaf(C.x, nx, fmaf(C.y, ny, fmaf(C.z, nz, C.w))) + qs;
}

// packed-key insertion into sorted-ascending 16: pure min/max chain
__device__ __forceinline__ void insU(unsigned (&bu)[16], unsigned k) {
#pragma unroll
    for (int m = 0; m < 16; m++) {
        unsigned mn = min(bu[m], k);
        k = max(bu[m], k);
        bu[m] = mn;
    }
}

// exact (float,int) sorted insertion for the final reorder
__device__ __forceinline__ void insert16(float (&bd)[16], int (&bi)[16], float cd, int ci) {
#pragma unroll
    for (int m = 0; m < 16; m++) {
        bool sw = cd < bd[m];
        float td = sw ? bd[m] : cd;
        int   ti = sw ? bi[m] : ci;
        bd[m] = sw ? cd : bd[m];
        bi[m] = sw ? ci : bi[m];
        cd = td; ci = ti;
    }
}

// ---- Kernel 1: KNN + geometry, lane-remapped ----
// Block = 64 queries x 8 segments (512 thr). Lane l: seg = l&7, query = t>>3.
// Scan: top-16 per (query,seg) by packed key (21-bit dist prefix | 11-bit idx);
// threshold shared across the 8 seg-lanes of a query via shfl_xor min at each
// flush (exact-fresh, no LDS). Seg s scans its 256 candidates starting at
// offset s: the 8 broadcast b128 reads tile all 32 LDS banks (conflict-free).
// Merge: 3 rounds of in-register bitonic merge across lanes (reversed-shuffle
// half-cleaner + 4-stage bitonic sort) -> every lane holds union-top-16 keys.
// Every true top-16 key passes each lane's threshold (any posted bound is some
// lane's 16th-seen >= union 16th), so union coverage is exact in key space;
// fillers (0xFFFFFFFF) lose all mins. Exact f32 distances recomputed for the
// 16 winners (stable (d,j) order), then cov/QR/dc geometry from LDS cloud.
__global__ __launch_bounds__(512, 6) void knn_geom_kernel(const float* __restrict__ pos,
                                                          float* __restrict__ dcn) {
    __shared__ float4 cloud[P_];                 // 32 KB
    int b = blockIdx.x >> 5, tile = blockIdx.x & 31;
    int base = b * P_;
    int t = threadIdx.x;
#pragma unroll
    for (int j = t; j < P_; j += 512) {
        float x = pos[(base + j) * 3 + 0];
        float y = pos[(base + j) * 3 + 1];
        float z = pos[(base + j) * 3 + 2];
        cloud[j] = make_float4(x, y, z, x * x + y * y + z * z);
    }
    __syncthreads();

    int s = t & 7;                                // segment lane
    int il = tile * QPB_ + (t >> 3);              // this lane's query
    float4 Q = cloud[il];
    float nx = -2.f * Q.x, ny = -2.f * Q.y, nz = -2.f * Q.z, qs = Q.w;
    int il_self = (s == (il >> 8)) ? il : -1;     // only the owning seg excludes self

    unsigned bu[16];
#pragma unroll
    for (int m = 0; m < 16; m++) bu[m] = 0xFFFFFFFFu;
    unsigned e0 = ~0u, e1 = ~0u, e2 = ~0u, e3 = ~0u, e4 = ~0u, e5 = ~0u;
    unsigned thr = 0xFFFFFFFFu;

    int j0 = s << 8;
    int c = s;                                    // staggered start (bank spread)
    float4 C = cloud[j0 | c];
    for (int jj = 0; jj < SEGLEN_; jj++) {
        int cn = (c + 1) & 255;
        float4 Cn = cloud[j0 | cn];               // prefetch
        int j = j0 | c;
        float d = distf(C, nx, ny, nz, qs);
        unsigned key = (__float_as_uint(fmaxf(d, 0.f)) & 0xFFFFF800u) | (unsigned)j;
        bool acc = (key < thr) && (j != il_self);
        e5 = acc ? e4 : e5;
        e4 = acc ? e3 : e4;
        e3 = acc ? e2 : e3;
        e2 = acc ? e1 : e2;
        e1 = acc ? e0 : e1;
        e0 = acc ? key : e0;
        if (__any(e5 != 0xFFFFFFFFu)) {           // some lane buffered 6 accepts
            insU(bu, e5); insU(bu, e4); insU(bu, e3);
            insU(bu, e2); insU(bu, e1); insU(bu, e0);
            e0 = e1 = e2 = e3 = e4 = e5 = 0xFFFFFFFFu;
            unsigned t16 = bu[15];                // share threshold across the 8 seg-lanes
            t16 = min(t16, (unsigned)__shfl_xor((int)t16, 1, 64));
            t16 = min(t16, (unsigned)__shfl_xor((int)t16, 2, 64));
            t16 = min(t16, (unsigned)__shfl_xor((int)t16, 4, 64));
            thr = min(thr, t16);
        }
        C = Cn; c = cn;
    }
    insU(bu, e5); insU(bu, e4); insU(bu, e3);
    insU(bu, e2); insU(bu, e1); insU(bu, e0);

    // ---- cross-lane merge: after 3 rounds every lane holds union-top-16 ----
#pragma unroll
    for (int mask = 1; mask <= 4; mask <<= 1) {
        unsigned o[16];
#pragma unroll
        for (int i = 0; i < 16; i++)
            o[i] = (unsigned)__shfl_xor((int)bu[15 - i], mask, 64);  // partner reversed
#pragma unroll
        for (int i = 0; i < 16; i++) bu[i] = min(bu[i], o[i]);       // half-cleaner
#pragma unroll
        for (int dd = 8; dd >= 1; dd >>= 1)                          // bitonic sort asc
#pragma unroll
            for (int k2 = 0; k2 < 16; k2 += 2 * dd)
#pragma unroll
                for (int i2 = k2; i2 < k2 + dd; i2++) {
                    unsigned mn = min(bu[i2], bu[i2 + dd]);
                    bu[i2 + dd] = max(bu[i2], bu[i2 + dd]);
                    bu[i2] = mn;
                }
    }

    // ---- exact reorder: recompute f32 distances, stable (d, j) ----
    float md[16]; int mi[16];
#pragma unroll
    for (int m = 0; m < 16; m++) { md[m] = INFINITY; mi[m] = 0; }
#pragma unroll
    for (int m = 0; m < 16; m++) {
        int j = bu[m] & 0x7FF;
        float4 Cm = cloud[j];
        insert16(md, mi, distf(Cm, nx, ny, nz, qs), j);
    }

    // ---- geometry: cov over L=8, 5x QR (LAPACK Householder), dc ----
    float px = Q.x, py = Q.y, pz = Q.z;
    float A[3][3];
    {
        float a00 = 0, a01 = 0, a02 = 0, a11 = 0, a12 = 0, a22 = 0;
#pragma unroll
        for (int l = 0; l < L_; l++) {
            float4 Cv = cloud[mi[l]];
            float ccx = Cv.x - px, ccy = Cv.y - py, ccz = Cv.z - pz;
            a00 += ccx * ccx; a01 += ccx * ccy; a02 += ccx * ccz;
            a11 += ccy * ccy; a12 += ccy * ccz; a22 += ccz * ccz;
        }
        A[0][0] = a00; A[0][1] = a01; A[0][2] = a02;
        A[1][0] = a01; A[1][1] = a11; A[1][2] = a12;
        A[2][0] = a02; A[2][1] = a12; A[2][2] = a22;
    }
    float Vt[3][3] = {{1.f, 0.f, 0.f}, {0.f, 1.f, 0.f}, {0.f, 0.f, 1.f}};

    for (int it = 0; it < 5; it++) {
        float M00 = A[0][0], M01 = A[0][1], M02 = A[0][2];
        float M10 = A[1][0], M11 = A[1][1], M12 = A[1][2];
        float M20 = A[2][0], M21 = A[2][1], M22 = A[2][2];
        float tau0 = 0.f, v1 = 0.f, v2 = 0.f;
        float xn2 = M10 * M10 + M20 * M20;
        if (xn2 != 0.f) {
            float beta = -copysignf(sqrtf(M00 * M00 + xn2), M00);
            tau0 = (beta - M00) / beta;
            float inv = 1.f / (M00 - beta);
            v1 = M10 * inv; v2 = M20 * inv;
            float sc;
            sc = tau0 * (M01 + v1 * M11 + v2 * M21); M01 -= sc; M11 -= v1 * sc; M21 -= v2 * sc;
            sc = tau0 * (M02 + v1 * M12 + v2 * M22); M02 -= sc; M12 -= v1 * sc; M22 -= v2 * sc;
            M00 = beta;
        }
        float tau1 = 0.f, u2 = 0.f;
        if (M21 != 0.f) {
            float beta1 = -copysignf(sqrtf(M11 * M11 + M21 * M21), M11);
            tau1 = (beta1 - M11) / beta1;
            u2 = M21 / (M11 - beta1);
            float sc = tau1 * (M12 + u2 * M22); M12 -= sc; M22 -= u2 * sc;
            M11 = beta1;
        }
        float h11 = 1.f - tau1, h12 = -tau1 * u2, h22 = 1.f - tau1 * u2 * u2;
        float Qm[3][3];
        Qm[0][0] = 1.f - tau0;
        Qm[1][0] = -v1 * tau0;
        Qm[2][0] = -v2 * tau0;
        float t1 = tau0 * (v1 * h11 + v2 * h12);
        Qm[0][1] = -t1;
        Qm[1][1] = h11 - v1 * t1;
        Qm[2][1] = h12 - v2 * t1;
        float t2 = tau0 * (v1 * h12 + v2 * h22);
        Qm[0][2] = -t2;
        Qm[1][2] = h12 - v1 * t2;
        Qm[2][2] = h22 - v2 * t2;
        A[0][0] = M00 * Qm[0][0] + M01 * Qm[1][0] + M02 * Qm[2][0];
        A[0][1] = M00 * Qm[0][1] + M01 * Qm[1][1] + M02 * Qm[2][1];
        A[0][2] = M00 * Qm[0][2] + M01 * Qm[1][2] + M02 * Qm[2][2];
        A[1][0] = M11 * Qm[1][0] + M12 * Qm[2][0];
        A[1][1] = M11 * Qm[1][1] + M12 * Qm[2][1];
        A[1][2] = M11 * Qm[1][2] + M12 * Qm[2][2];
        A[2][0] = M22 * Qm[2][0];
        A[2][1] = M22 * Qm[2][1];
        A[2][2] = M22 * Qm[2][2];
        float nv[3][3];
#pragma unroll
        for (int r = 0; r < 3; r++)
#pragma unroll
            for (int cc = 0; cc < 3; cc++)
                nv[r][cc] = Vt[r][0] * Qm[0][cc] + Vt[r][1] * Qm[1][cc] + Vt[r][2] * Qm[2][cc];
#pragma unroll
        for (int r = 0; r < 3; r++)
#pragma unroll
            for (int cc = 0; cc < 3; cc++) Vt[r][cc] = nv[r][cc];
    }

    // pass B: z-column sum + abs-max (recompute c from LDS)
    float s2 = 0.f, mx01 = 0.f, mx2 = 0.f;
#pragma unroll
    for (int k = 0; k < K_; k++) {
        float4 Cv = cloud[mi[k]];
        float ccx = Cv.x - px, ccy = Cv.y - py, ccz = Cv.z - pz;
        float d0 = ccx * Vt[0][0] + ccy * Vt[1][0] + ccz * Vt[2][0];
        float d1 = ccx * Vt[0][1] + ccy * Vt[1][1] + ccz * Vt[2][1];
        float d2 = ccx * Vt[0][2] + ccy * Vt[1][2] + ccz * Vt[2][2];
        s2 += d2;
        mx01 = fmaxf(mx01, fmaxf(fabsf(d0), fabsf(d1)));
        mx2  = fmaxf(mx2, fabsf(d2));
    }
    float sg = (s2 > 0.f) ? 1.f : ((s2 < 0.f) ? -1.f : 0.f);
    float mx = fmaxf(mx01, (sg == 0.f) ? 0.f : mx2);
    float hs = 0.5f / mx;

    // pass C: project, normalize, write (lane s==0 of each query group)
    if (s == 0) {
        int i = base + il;
        float4* row = (float4*)(dcn + (size_t)i * 48);
#pragma unroll
        for (int g = 0; g < 4; g++) {
            float v[12];
#pragma unroll
            for (int kk = 0; kk < 4; kk++) {
                int k = g * 4 + kk;
                float4 Cv = cloud[mi[k]];
                float ccx = Cv.x - px, ccy = Cv.y - py, ccz = Cv.z - pz;
                float d0 = ccx * Vt[0][0] + ccy * Vt[1][0] + ccz * Vt[2][0];
                float d1 = ccx * Vt[0][1] + ccy * Vt[1][1] + ccz * Vt[2][1];
                float d2 = (ccx * Vt[0][2] + ccy * Vt[1][2] + ccz * Vt[2][2]) * sg;
                v[kk * 3 + 0] = d0 * hs + 0.5f;
                v[kk * 3 + 1] = d1 * hs + 0.5f;
                v[kk * 3 + 2] = d2 * hs + 0.5f;
            }
#pragma unroll
            for (int r = 0; r < 3; r++)
                row[g * 3 + r] = make_float4(v[r * 4 + 0], v[r * 4 + 1],
                                             v[r * 4 + 2], v[r * 4 + 3]);
        }
    }
}

// ---------- Kernel 2: trilinear spline gather + out_nondir + BN partials -----
__global__ __launch_bounds__(256) void spline_kernel(const float* __restrict__ dcn,
                                                     const float* __restrict__ w_spline,
                                                     const float* __restrict__ w_root,
                                                     const float* __restrict__ b_spline,
                                                     float* __restrict__ x,
                                                     float* __restrict__ partials) {
    __shared__ float ws_t[F_ * KS3_];   // [f][cell], 32000 B
    __shared__ float red[4][64];
    {
        int f = threadIdx.x & 63;
        for (int c = threadIdx.x >> 6; c < KS3_; c += 4)
            ws_t[f * KS3_ + c] = w_spline[c * 64 + f];
    }
    __syncthreads();
    int wave = threadIdx.x >> 6, f = threadIdx.x & 63;
    const float* wbase = &ws_t[f * KS3_];
    float wr = w_root[f] + b_spline[f];
    float s1 = 0.f, s2 = 0.f;
    for (int p = 0; p < 16; p++) {
        int i = blockIdx.x * 64 + wave * 16 + p;
        const float4* row = (const float4*)(dcn + (size_t)i * 48);
        float pr[48];
#pragma unroll
        for (int m = 0; m < 12; m++) {
            float4 v = row[m];
            pr[m * 4 + 0] = v.x; pr[m * 4 + 1] = v.y;
            pr[m * 4 + 2] = v.z; pr[m * 4 + 3] = v.w;
        }
        float acc = 0.f;
#pragma unroll
        for (int k = 0; k < K_; k++) {
            float p0 = pr[k * 3 + 0] * 4.f;
            float p1 = pr[k * 3 + 1] * 4.f;
            float p2 = pr[k * 3 + 2] * 4.f;
            float i0 = fminf(fmaxf(floorf(p0), 0.f), 3.f);
            float i1 = fminf(fmaxf(floorf(p1), 0.f), 3.f);
            float i2 = fminf(fmaxf(floorf(p2), 0.f), 3.f);
            float f0 = p0 - i0, f1 = p1 - i1, f2 = p2 - i2;
            float g0 = 1.f - f0, g1 = 1.f - f1, g2 = 1.f - f2;
            int c = (int)fmaf(i2, 25.f, fmaf(i1, 5.f, i0));
            const float* wp = wbase + c;
            float a0 = wp[0],  a1 = wp[1];
            float b0 = wp[5],  b1v = wp[6];
            float c0 = wp[25], c1 = wp[26];
            float d0 = wp[30], d1 = wp[31];
            float wA = g1 * g2, wB = f1 * g2, wC = g1 * f2, wD = f1 * f2;
            acc = fmaf(wA, fmaf(f0, a1, g0 * a0), acc);
            acc = fmaf(wB, fmaf(f0, b1v, g0 * b0), acc);
            acc = fmaf(wC, fmaf(f0, c1, g0 * c0), acc);
            acc = fmaf(wD, fmaf(f0, d1, g0 * d0), acc);
        }
        float xv = acc * (1.f / 16.f) + wr;
        x[(size_t)i * 64 + f] = xv;
        s1 += xv; s2 += xv * xv;
    }
    red[wave][f] = s1; __syncthreads();
    if (threadIdx.x < 64)
        partials[blockIdx.x * 128 + f] = red[0][f] + red[1][f] + red[2][f] + red[3][f];
    __syncthreads();
    red[wave][f] = s2; __syncthreads();
    if (threadIdx.x < 64)
        partials[blockIdx.x * 128 + 64 + f] = red[0][f] + red[1][f] + red[2][f] + red[3][f];
}

// ----------------------- Kernel 3: BN stats finalize -------------------------
__global__ __launch_bounds__(256) void stats_kernel(const float* __restrict__ partials,
                                                    const float* __restrict__ gamma,
                                                    const float* __restrict__ beta,
                                                    float* __restrict__ stats) {
    __shared__ double red1[256], red2[256];
    int t = threadIdx.x;
    int f = t & 63, g = t >> 6;
    double a0 = 0, a1 = 0, a2 = 0, a3 = 0, q0 = 0, q1 = 0, q2 = 0, q3 = 0;
    for (int b2 = g; b2 < 1024; b2 += 16) {
        a0 += (double)partials[(b2     ) * 128 + f];
        q0 += (double)partials[(b2     ) * 128 + 64 + f];
        a1 += (double)partials[(b2 +  4) * 128 + f];
        q1 += (double)partials[(b2 +  4) * 128 + 64 + f];
        a2 += (double)partials[(b2 +  8) * 128 + f];
        q2 += (double)partials[(b2 +  8) * 128 + 64 + f];
        a3 += (double)partials[(b2 + 12) * 128 + f];
        q3 += (double)partials[(b2 + 12) * 128 + 64 + f];
    }
    red1[t] = (a0 + a1) + (a2 + a3);
    red2[t] = (q0 + q1) + (q2 + q3);
    __syncthreads();
    if (t < 64) {
        double S1 = red1[t] + red1[t + 64] + red1[t + 128] + red1[t + 192];
        double S2 = red2[t] + red2[t + 64] + red2[t + 128] + red2[t + 192];
        double mu = S1 / (double)N_;
        double var = S2 / (double)N_ - mu * mu;
        double scale = (double)gamma[t] / sqrt(var + (double)EPS_);
        double shift = (double)beta[t] - mu * scale;
        stats[t] = (float)scale;
        stats[64 + t] = (float)shift;
    }
}

// -------------- Kernel 4: sigmoid + per-batch-chunk partial pool -------------
__global__ __launch_bounds__(256) void pool_partial_kernel(const float* __restrict__ x,
                                                           const float* __restrict__ stats,
                                                           float* __restrict__ pp) {
    __shared__ float red[4][64];
    int blk = blockIdx.x;            // 32 batches * 32 chunks of 64 rows
    int b = blk >> 5, ch = blk & 31;
    int f = threadIdx.x & 63, w = threadIdx.x >> 6;
    float scale = stats[f], shift = stats[64 + f];
    float acc = 0.f;
    int row0 = b * P_ + ch * 64;
    for (int r = w; r < 64; r += 4) {
        float v = x[(size_t)(row0 + r) * 64 + f];
        float t = fmaf(v, scale, shift);
        acc += __fdividef(1.f, 1.f + __expf(-t));
    }
    red[w][f] = acc; __syncthreads();
    if (threadIdx.x < 64) pp[blk * 64 + f] = red[0][f] + red[1][f] + red[2][f] + red[3][f];
}

// ------------------ Kernel 5: batch means + GEMM1 + ELU ----------------------
__global__ __launch_bounds__(256) void mlp1_kernel(const float* __restrict__ pp,
                                                   const float* __restrict__ w1,
                                                   const float* __restrict__ b1,
                                                   float* __restrict__ y1) {
    __shared__ float ssy[64];
    int b = blockIdx.x, t = threadIdx.x;
    if (t < 64) {
        float s = 0.f;
#pragma unroll
        for (int g = 0; g < 32; g++) s += pp[(b * 32 + g) * 64 + t];
        ssy[t] = s * (1.f / 2048.f);
    }
    __syncthreads();
    float acc = b1[t];
#pragma unroll 8
    for (int c = 0; c < F_; c++) acc = fmaf(ssy[c], w1[c * 256 + t], acc);
    y1[b * 256 + t] = acc > 0.f ? acc : expm1f(acc);
}

// ------------------ Kernel 6: GEMM2 + log_softmax (wave-wide) ----------------
__global__ __launch_bounds__(64) void mlp2_kernel(const float* __restrict__ y1,
                                                  const float* __restrict__ w2,
                                                  const float* __restrict__ b2,
                                                  float* __restrict__ out) {
    int b = blockIdx.x, j = threadIdx.x;
    float acc = -INFINITY;
    if (j < NC_) {
        acc = b2[j];
#pragma unroll 8
        for (int c = 0; c < H_; c++) acc = fmaf(y1[b * 256 + c], w2[c * 40 + j], acc);
    }
    float m = acc;
#pragma unroll
    for (int o = 32; o > 0; o >>= 1) m = fmaxf(m, __shfl_xor(m, o, 64));
    float e = (j < NC_) ? expf(acc - m) : 0.f;
    float s = e;
#pragma unroll
    for (int o = 32; o > 0; o >>= 1) s += __shfl_xor(s, o, 64);
    if (j < NC_) out[b * NC_ + j] = acc - m - logf(s);
}

extern "C" void kernel_launch(void* const* d_in, const int* in_sizes, int n_in,
                              void* d_out, int out_size, void* d_ws, size_t ws_size,
                              hipStream_t stream) {
    const float* pos      = (const float*)d_in[0];
    const float* w_spline = (const float*)d_in[2];
    const float* w_root   = (const float*)d_in[3];
    const float* b_spline = (const float*)d_in[4];
    const float* bn_gamma = (const float*)d_in[5];
    const float* bn_beta  = (const float*)d_in[6];
    const float* w1       = (const float*)d_in[7];
    const float* b1       = (const float*)d_in[8];
    const float* w2       = (const float*)d_in[9];
    const float* b2       = (const float*)d_in[10];
    float* out = (float*)d_out;

    char* ws = (char*)d_ws;
    float* dcn      = (float*)(ws + 0);                    // 12 MB
    float* x        = (float*)(ws + (12u << 20));          // 16 MB
    float* partials = (float*)(ws + (28u << 20));          // 512 KB
    float* stats    = (float*)(ws + (28u << 20) + (512u << 10));               // 4 KB slot
    float* pp       = (float*)(ws + (28u << 20) + (512u << 10) + 4096);        // 256 KB
    float* y1       = (float*)(ws + (28u << 20) + (512u << 10) + 4096 + (256u << 10)); // 32 KB

    knn_geom_kernel<<<B_ * 32, 512, 0, stream>>>(pos, dcn);
    spline_kernel<<<N_ / 64, 256, 0, stream>>>(dcn, w_spline, w_root, b_spline, x, partials);
    stats_kernel<<<1, 256, 0, stream>>>(partials, bn_gamma, bn_beta, stats);
    pool_partial_kernel<<<B_ * 32, 256, 0, stream>>>(x, stats, pp);
    mlp1_kernel<<<B_, 256, 0, stream>>>(pp, w1, b1, y1);
    mlp2_kernel<<<B_, 64, 0, stream>>>(y1, w2, b2, out);
}

// Round 9
// 254.357 us; speedup vs baseline: 1.0108x; 1.0108x over previous
//
#include <hip/hip_runtime.h>
#include <math.h>

#define B_ 32
#define P_ 2048
#define N_ 65536
#define K_ 16
#define L_ 8
#define F_ 64
#define KS_ 5
#define KS3_ 125
#define NC_ 40
#define H_ 256
#define EPS_ 1e-5f
#define QPB_ 64
#define SEGLEN_ 256

// exact same fp expression everywhere (pinned fmaf order)
__device__ __forceinline__ float distf(float4 C, float nx, float ny, float nz, float qs) {
    return fmaf(C.x, nx, fmaf(C.y, ny, fmaf(C.z, nz, C.w))) + qs;
}

// packed-key insertion into sorted-ascending 16: pure min/max chain
__device__ __forceinline__ void insU(unsigned (&bu)[16], unsigned k) {
#pragma unroll
    for (int m = 0; m < 16; m++) {
        unsigned mn = min(bu[m], k);
        k = max(bu[m], k);
        bu[m] = mn;
    }
}

// exact (float,int) sorted insertion for the final reorder
__device__ __forceinline__ void insert16(float (&bd)[16], int (&bi)[16], float cd, int ci) {
#pragma unroll
    for (int m = 0; m < 16; m++) {
        bool sw = cd < bd[m];
        float td = sw ? bd[m] : cd;
        int   ti = sw ? bi[m] : ci;
        bd[m] = sw ? cd : bd[m];
        bi[m] = sw ? ci : bi[m];
        cd = td; ci = ti;
    }
}

// ---- Kernel 1: KNN + geometry, lane-remapped ----
// Block = 64 queries x 8 segments (512 thr). Lane l: seg = l&7, query = t>>3.
// Scan: top-16 per (query,seg) by packed key (21-bit dist prefix | 11-bit idx);
// threshold shared across the 8 seg-lanes of a query via shfl_xor min at each
// flush (exact-fresh, no LDS). Seg s scans its 256 candidates starting at
// offset s: the 8 broadcast b128 reads tile all 32 LDS banks (conflict-free).
// Merge: 3 rounds of in-register bitonic merge across lanes (reversed-shuffle
// half-cleaner + 4-stage bitonic sort) -> every lane holds union-top-16 keys.
// Every true top-16 key passes each lane's threshold (any posted bound is some
// lane's 16th-seen >= union 16th), so union coverage is exact in key space;
// fillers (0xFFFFFFFF) lose all mins. Exact f32 distances recomputed for the
// 16 winners (stable (d,j) order), then cov/QR/dc geometry from LDS cloud.
// __launch_bounds__(512, 4): VGPR cap 128 -- peak live set (bu+md+mi+frame)
// ~80 regs fits with NO scratch spill (the (512,6) cap of ~85 forced 226 MB
// of spill traffic per dispatch in round 8).
__global__ __launch_bounds__(512, 4) void knn_geom_kernel(const float* __restrict__ pos,
                                                          float* __restrict__ dcn) {
    __shared__ float4 cloud[P_];                 // 32 KB
    int b = blockIdx.x >> 5, tile = blockIdx.x & 31;
    int base = b * P_;
    int t = threadIdx.x;
    for (int j = t; j < P_; j += 512) {
        float x = pos[(base + j) * 3 + 0];
        float y = pos[(base + j) * 3 + 1];
        float z = pos[(base + j) * 3 + 2];
        cloud[j] = make_float4(x, y, z, x * x + y * y + z * z);
    }
    __syncthreads();

    int s = t & 7;                                // segment lane
    int il = tile * QPB_ + (t >> 3);              // this lane's query
    float4 Q = cloud[il];
    float nx = -2.f * Q.x, ny = -2.f * Q.y, nz = -2.f * Q.z, qs = Q.w;
    int il_self = (s == (il >> 8)) ? il : -1;     // only the owning seg excludes self

    unsigned bu[16];
#pragma unroll
    for (int m = 0; m < 16; m++) bu[m] = 0xFFFFFFFFu;
    unsigned e0 = ~0u, e1 = ~0u, e2 = ~0u, e3 = ~0u, e4 = ~0u, e5 = ~0u;
    unsigned thr = 0xFFFFFFFFu;

    int j0 = s << 8;
    int c = s;                                    // staggered start (bank spread)
    float4 C = cloud[j0 | c];
    for (int jj = 0; jj < SEGLEN_; jj++) {
        int cn = (c + 1) & 255;
        float4 Cn = cloud[j0 | cn];               // prefetch
        int j = j0 | c;
        float d = distf(C, nx, ny, nz, qs);
        unsigned key = (__float_as_uint(fmaxf(d, 0.f)) & 0xFFFFF800u) | (unsigned)j;
        bool acc = (key < thr) && (j != il_self);
        e5 = acc ? e4 : e5;
        e4 = acc ? e3 : e4;
        e3 = acc ? e2 : e3;
        e2 = acc ? e1 : e2;
        e1 = acc ? e0 : e1;
        e0 = acc ? key : e0;
        if (__any(e5 != 0xFFFFFFFFu)) {           // some lane buffered 6 accepts
            insU(bu, e5); insU(bu, e4); insU(bu, e3);
            insU(bu, e2); insU(bu, e1); insU(bu, e0);
            e0 = e1 = e2 = e3 = e4 = e5 = 0xFFFFFFFFu;
            unsigned t16 = bu[15];                // share threshold across the 8 seg-lanes
            t16 = min(t16, (unsigned)__shfl_xor((int)t16, 1, 64));
            t16 = min(t16, (unsigned)__shfl_xor((int)t16, 2, 64));
            t16 = min(t16, (unsigned)__shfl_xor((int)t16, 4, 64));
            thr = min(thr, t16);
        }
        C = Cn; c = cn;
    }
    insU(bu, e5); insU(bu, e4); insU(bu, e3);
    insU(bu, e2); insU(bu, e1); insU(bu, e0);

    // ---- cross-lane merge: after 3 rounds every lane holds union-top-16 ----
#pragma unroll
    for (int mask = 1; mask <= 4; mask <<= 1) {
        unsigned o[16];
#pragma unroll
        for (int i = 0; i < 16; i++)
            o[i] = (unsigned)__shfl_xor((int)bu[15 - i], mask, 64);  // partner reversed
#pragma unroll
        for (int i = 0; i < 16; i++) bu[i] = min(bu[i], o[i]);       // half-cleaner
#pragma unroll
        for (int dd = 8; dd >= 1; dd >>= 1)                          // bitonic sort asc
#pragma unroll
            for (int k2 = 0; k2 < 16; k2 += 2 * dd)
#pragma unroll
                for (int i2 = k2; i2 < k2 + dd; i2++) {
                    unsigned mn = min(bu[i2], bu[i2 + dd]);
                    bu[i2 + dd] = max(bu[i2], bu[i2 + dd]);
                    bu[i2] = mn;
                }
    }

    // ---- exact reorder: recompute f32 distances, stable (d, j) ----
    float md[16]; int mi[16];
#pragma unroll
    for (int m = 0; m < 16; m++) { md[m] = INFINITY; mi[m] = 0; }
#pragma unroll
    for (int m = 0; m < 16; m++) {
        int j = bu[m] & 0x7FF;
        float4 Cm = cloud[j];
        insert16(md, mi, distf(Cm, nx, ny, nz, qs), j);
    }

    // ---- geometry: cov over L=8, 5x QR (LAPACK Householder), dc ----
    float px = Q.x, py = Q.y, pz = Q.z;
    float A[3][3];
    {
        float a00 = 0, a01 = 0, a02 = 0, a11 = 0, a12 = 0, a22 = 0;
#pragma unroll
        for (int l = 0; l < L_; l++) {
            float4 Cv = cloud[mi[l]];
            float ccx = Cv.x - px, ccy = Cv.y - py, ccz = Cv.z - pz;
            a00 += ccx * ccx; a01 += ccx * ccy; a02 += ccx * ccz;
            a11 += ccy * ccy; a12 += ccy * ccz; a22 += ccz * ccz;
        }
        A[0][0] = a00; A[0][1] = a01; A[0][2] = a02;
        A[1][0] = a01; A[1][1] = a11; A[1][2] = a12;
        A[2][0] = a02; A[2][1] = a12; A[2][2] = a22;
    }
    float Vt[3][3] = {{1.f, 0.f, 0.f}, {0.f, 1.f, 0.f}, {0.f, 0.f, 1.f}};

    for (int it = 0; it < 5; it++) {
        float M00 = A[0][0], M01 = A[0][1], M02 = A[0][2];
        float M10 = A[1][0], M11 = A[1][1], M12 = A[1][2];
        float M20 = A[2][0], M21 = A[2][1], M22 = A[2][2];
        float tau0 = 0.f, v1 = 0.f, v2 = 0.f;
        float xn2 = M10 * M10 + M20 * M20;
        if (xn2 != 0.f) {
            float beta = -copysignf(sqrtf(M00 * M00 + xn2), M00);
            tau0 = (beta - M00) / beta;
            float inv = 1.f / (M00 - beta);
            v1 = M10 * inv; v2 = M20 * inv;
            float sc;
            sc = tau0 * (M01 + v1 * M11 + v2 * M21); M01 -= sc; M11 -= v1 * sc; M21 -= v2 * sc;
            sc = tau0 * (M02 + v1 * M12 + v2 * M22); M02 -= sc; M12 -= v1 * sc; M22 -= v2 * sc;
            M00 = beta;
        }
        float tau1 = 0.f, u2 = 0.f;
        if (M21 != 0.f) {
            float beta1 = -copysignf(sqrtf(M11 * M11 + M21 * M21), M11);
            tau1 = (beta1 - M11) / beta1;
            u2 = M21 / (M11 - beta1);
            float sc = tau1 * (M12 + u2 * M22); M12 -= sc; M22 -= u2 * sc;
            M11 = beta1;
        }
        float h11 = 1.f - tau1, h12 = -tau1 * u2, h22 = 1.f - tau1 * u2 * u2;
        float Qm[3][3];
        Qm[0][0] = 1.f - tau0;
        Qm[1][0] = -v1 * tau0;
        Qm[2][0] = -v2 * tau0;
        float t1 = tau0 * (v1 * h11 + v2 * h12);
        Qm[0][1] = -t1;
        Qm[1][1] = h11 - v1 * t1;
        Qm[2][1] = h12 - v2 * t1;
        float t2 = tau0 * (v1 * h12 + v2 * h22);
        Qm[0][2] = -t2;
        Qm[1][2] = h12 - v1 * t2;
        Qm[2][2] = h22 - v2 * t2;
        A[0][0] = M00 * Qm[0][0] + M01 * Qm[1][0] + M02 * Qm[2][0];
        A[0][1] = M00 * Qm[0][1] + M01 * Qm[1][1] + M02 * Qm[2][1];
        A[0][2] = M00 * Qm[0][2] + M01 * Qm[1][2] + M02 * Qm[2][2];
        A[1][0] = M11 * Qm[1][0] + M12 * Qm[2][0];
        A[1][1] = M11 * Qm[1][1] + M12 * Qm[2][1];
        A[1][2] = M11 * Qm[1][2] + M12 * Qm[2][2];
        A[2][0] = M22 * Qm[2][0];
        A[2][1] = M22 * Qm[2][1];
        A[2][2] = M22 * Qm[2][2];
        float nv[3][3];
#pragma unroll
        for (int r = 0; r < 3; r++)
#pragma unroll
            for (int cc = 0; cc < 3; cc++)
                nv[r][cc] = Vt[r][0] * Qm[0][cc] + Vt[r][1] * Qm[1][cc] + Vt[r][2] * Qm[2][cc];
#pragma unroll
        for (int r = 0; r < 3; r++)
#pragma unroll
            for (int cc = 0; cc < 3; cc++) Vt[r][cc] = nv[r][cc];
    }

    // pass B: z-column sum + abs-max (recompute c from LDS)
    float s2 = 0.f, mx01 = 0.f, mx2 = 0.f;
#pragma unroll
    for (int k = 0; k < K_; k++) {
        float4 Cv = cloud[mi[k]];
        float ccx = Cv.x - px, ccy = Cv.y - py, ccz = Cv.z - pz;
        float d0 = ccx * Vt[0][0] + ccy * Vt[1][0] + ccz * Vt[2][0];
        float d1 = ccx * Vt[0][1] + ccy * Vt[1][1] + ccz * Vt[2][1];
        float d2 = ccx * Vt[0][2] + ccy * Vt[1][2] + ccz * Vt[2][2];
        s2 += d2;
        mx01 = fmaxf(mx01, fmaxf(fabsf(d0), fabsf(d1)));
        mx2  = fmaxf(mx2, fabsf(d2));
    }
    float sg = (s2 > 0.f) ? 1.f : ((s2 < 0.f) ? -1.f : 0.f);
    float mx = fmaxf(mx01, (sg == 0.f) ? 0.f : mx2);
    float hs = 0.5f / mx;

    // pass C: project, normalize, write (lane s==0 of each query group)
    if (s == 0) {
        int i = base + il;
        float4* row = (float4*)(dcn + (size_t)i * 48);
#pragma unroll
        for (int g = 0; g < 4; g++) {
            float v[12];
#pragma unroll
            for (int kk = 0; kk < 4; kk++) {
                int k = g * 4 + kk;
                float4 Cv = cloud[mi[k]];
                float ccx = Cv.x - px, ccy = Cv.y - py, ccz = Cv.z - pz;
                float d0 = ccx * Vt[0][0] + ccy * Vt[1][0] + ccz * Vt[2][0];
                float d1 = ccx * Vt[0][1] + ccy * Vt[1][1] + ccz * Vt[2][1];
                float d2 = (ccx * Vt[0][2] + ccy * Vt[1][2] + ccz * Vt[2][2]) * sg;
                v[kk * 3 + 0] = d0 * hs + 0.5f;
                v[kk * 3 + 1] = d1 * hs + 0.5f;
                v[kk * 3 + 2] = d2 * hs + 0.5f;
            }
#pragma unroll
            for (int r = 0; r < 3; r++)
                row[g * 3 + r] = make_float4(v[r * 4 + 0], v[r * 4 + 1],
                                             v[r * 4 + 2], v[r * 4 + 3]);
        }
    }
}

// ---------- Kernel 2: trilinear spline gather + out_nondir + BN partials -----
__global__ __launch_bounds__(256) void spline_kernel(const float* __restrict__ dcn,
                                                     const float* __restrict__ w_spline,
                                                     const float* __restrict__ w_root,
                                                     const float* __restrict__ b_spline,
                                                     float* __restrict__ x,
                                                     float* __restrict__ partials) {
    __shared__ float ws_t[F_ * KS3_];   // [f][cell], 32000 B
    __shared__ float red[4][64];
    {
        int f = threadIdx.x & 63;
        for (int c = threadIdx.x >> 6; c < KS3_; c += 4)
            ws_t[f * KS3_ + c] = w_spline[c * 64 + f];
    }
    __syncthreads();
    int wave = threadIdx.x >> 6, f = threadIdx.x & 63;
    const float* wbase = &ws_t[f * KS3_];
    float wr = w_root[f] + b_spline[f];
    float s1 = 0.f, s2 = 0.f;
    for (int p = 0; p < 16; p++) {
        int i = blockIdx.x * 64 + wave * 16 + p;
        const float4* row = (const float4*)(dcn + (size_t)i * 48);
        float pr[48];
#pragma unroll
        for (int m = 0; m < 12; m++) {
            float4 v = row[m];
            pr[m * 4 + 0] = v.x; pr[m * 4 + 1] = v.y;
            pr[m * 4 + 2] = v.z; pr[m * 4 + 3] = v.w;
        }
        float acc = 0.f;
#pragma unroll
        for (int k = 0; k < K_; k++) {
            float p0 = pr[k * 3 + 0] * 4.f;
            float p1 = pr[k * 3 + 1] * 4.f;
            float p2 = pr[k * 3 + 2] * 4.f;
            float i0 = fminf(fmaxf(floorf(p0), 0.f), 3.f);
            float i1 = fminf(fmaxf(floorf(p1), 0.f), 3.f);
            float i2 = fminf(fmaxf(floorf(p2), 0.f), 3.f);
            float f0 = p0 - i0, f1 = p1 - i1, f2 = p2 - i2;
            float g0 = 1.f - f0, g1 = 1.f - f1, g2 = 1.f - f2;
            int c = (int)fmaf(i2, 25.f, fmaf(i1, 5.f, i0));
            const float* wp = wbase + c;
            float a0 = wp[0],  a1 = wp[1];
            float b0 = wp[5],  b1v = wp[6];
            float c0 = wp[25], c1 = wp[26];
            float d0 = wp[30], d1 = wp[31];
            float wA = g1 * g2, wB = f1 * g2, wC = g1 * f2, wD = f1 * f2;
            acc = fmaf(wA, fmaf(f0, a1, g0 * a0), acc);
            acc = fmaf(wB, fmaf(f0, b1v, g0 * b0), acc);
            acc = fmaf(wC, fmaf(f0, c1, g0 * c0), acc);
            acc = fmaf(wD, fmaf(f0, d1, g0 * d0), acc);
        }
        float xv = acc * (1.f / 16.f) + wr;
        x[(size_t)i * 64 + f] = xv;
        s1 += xv; s2 += xv * xv;
    }
    red[wave][f] = s1; __syncthreads();
    if (threadIdx.x < 64)
        partials[blockIdx.x * 128 + f] = red[0][f] + red[1][f] + red[2][f] + red[3][f];
    __syncthreads();
    red[wave][f] = s2; __syncthreads();
    if (threadIdx.x < 64)
        partials[blockIdx.x * 128 + 64 + f] = red[0][f] + red[1][f] + red[2][f] + red[3][f];
}

// ----------------------- Kernel 3: BN stats finalize -------------------------
__global__ __launch_bounds__(256) void stats_kernel(const float* __restrict__ partials,
                                                    const float* __restrict__ gamma,
                                                    const float* __restrict__ beta,
                                                    float* __restrict__ stats) {
    __shared__ double red1[256], red2[256];
    int t = threadIdx.x;
    int f = t & 63, g = t >> 6;
    double a0 = 0, a1 = 0, a2 = 0, a3 = 0, q0 = 0, q1 = 0, q2 = 0, q3 = 0;
    for (int b2 = g; b2 < 1024; b2 += 16) {
        a0 += (double)partials[(b2     ) * 128 + f];
        q0 += (double)partials[(b2     ) * 128 + 64 + f];
        a1 += (double)partials[(b2 +  4) * 128 + f];
        q1 += (double)partials[(b2 +  4) * 128 + 64 + f];
        a2 += (double)partials[(b2 +  8) * 128 + f];
        q2 += (double)partials[(b2 +  8) * 128 + 64 + f];
        a3 += (double)partials[(b2 + 12) * 128 + f];
        q3 += (double)partials[(b2 + 12) * 128 + 64 + f];
    }
    red1[t] = (a0 + a1) + (a2 + a3);
    red2[t] = (q0 + q1) + (q2 + q3);
    __syncthreads();
    if (t < 64) {
        double S1 = red1[t] + red1[t + 64] + red1[t + 128] + red1[t + 192];
        double S2 = red2[t] + red2[t + 64] + red2[t + 128] + red2[t + 192];
        double mu = S1 / (double)N_;
        double var = S2 / (double)N_ - mu * mu;
        double scale = (double)gamma[t] / sqrt(var + (double)EPS_);
        double shift = (double)beta[t] - mu * scale;
        stats[t] = (float)scale;
        stats[64 + t] = (float)shift;
    }
}

// -------------- Kernel 4: sigmoid + per-batch-chunk partial pool -------------
__global__ __launch_bounds__(256) void pool_partial_kernel(const float* __restrict__ x,
                                                           const float* __restrict__ stats,
                                                           float* __restrict__ pp) {
    __shared__ float red[4][64];
    int blk = blockIdx.x;            // 32 batches * 32 chunks of 64 rows
    int b = blk >> 5, ch = blk & 31;
    int f = threadIdx.x & 63, w = threadIdx.x >> 6;
    float scale = stats[f], shift = stats[64 + f];
    float acc = 0.f;
    int row0 = b * P_ + ch * 64;
    for (int r = w; r < 64; r += 4) {
        float v = x[(size_t)(row0 + r) * 64 + f];
        float t = fmaf(v, scale, shift);
        acc += __fdividef(1.f, 1.f + __expf(-t));
    }
    red[w][f] = acc; __syncthreads();
    if (threadIdx.x < 64) pp[blk * 64 + f] = red[0][f] + red[1][f] + red[2][f] + red[3][f];
}

// ------------------ Kernel 5: batch means + GEMM1 + ELU ----------------------
__global__ __launch_bounds__(256) void mlp1_kernel(const float* __restrict__ pp,
                                                   const float* __restrict__ w1,
                                                   const float* __restrict__ b1,
                                                   float* __restrict__ y1) {
    __shared__ float ssy[64];
    int b = blockIdx.x, t = threadIdx.x;
    if (t < 64) {
        float s = 0.f;
#pragma unroll
        for (int g = 0; g < 32; g++) s += pp[(b * 32 + g) * 64 + t];
        ssy[t] = s * (1.f / 2048.f);
    }
    __syncthreads();
    float acc = b1[t];
#pragma unroll 8
    for (int c = 0; c < F_; c++) acc = fmaf(ssy[c], w1[c * 256 + t], acc);
    y1[b * 256 + t] = acc > 0.f ? acc : expm1f(acc);
}

// ------------------ Kernel 6: GEMM2 + log_softmax (wave-wide) ----------------
__global__ __launch_bounds__(64) void mlp2_kernel(const float* __restrict__ y1,
                                                  const float* __restrict__ w2,
                                                  const float* __restrict__ b2,
                                                  float* __restrict__ out) {
    int b = blockIdx.x, j = threadIdx.x;
    float acc = -INFINITY;
    if (j < NC_) {
        acc = b2[j];
#pragma unroll 8
        for (int c = 0; c < H_; c++) acc = fmaf(y1[b * 256 + c], w2[c * 40 + j], acc);
    }
    float m = acc;
#pragma unroll
    for (int o = 32; o > 0; o >>= 1) m = fmaxf(m, __shfl_xor(m, o, 64));
    float e = (j < NC_) ? expf(acc - m) : 0.f;
    float s = e;
#pragma unroll
    for (int o = 32; o > 0; o >>= 1) s += __shfl_xor(s, o, 64);
    if (j < NC_) out[b * NC_ + j] = acc - m - logf(s);
}

extern "C" void kernel_launch(void* const* d_in, const int* in_sizes, int n_in,
                              void* d_out, int out_size, void* d_ws, size_t ws_size,
                              hipStream_t stream) {
    const float* pos      = (const float*)d_in[0];
    const float* w_spline = (const float*)d_in[2];
    const float* w_root   = (const float*)d_in[3];
    const float* b_spline = (const float*)d_in[4];
    const float* bn_gamma = (const float*)d_in[5];
    const float* bn_beta  = (const float*)d_in[6];
    const float* w1       = (const float*)d_in[7];
    const float* b1       = (const float*)d_in[8];
    const float* w2       = (const float*)d_in[9];
    const float* b2       = (const float*)d_in[10];
    float* out = (float*)d_out;

    char* ws = (char*)d_ws;
    float* dcn      = (float*)(ws + 0);                    // 12 MB
    float* x        = (float*)(ws + (12u << 20));          // 16 MB
    float* partials = (float*)(ws + (28u << 20));          // 512 KB
    float* stats    = (float*)(ws + (28u << 20) + (512u << 10));               // 4 KB slot
    float* pp       = (float*)(ws + (28u << 20) + (512u << 10) + 4096);        // 256 KB
    float* y1       = (float*)(ws + (28u << 20) + (512u << 10) + 4096 + (256u << 10)); // 32 KB

    knn_geom_kernel<<<B_ * 32, 512, 0, stream>>>(pos, dcn);
    spline_kernel<<<N_ / 64, 256, 0, stream>>>(dcn, w_spline, w_root, b_spline, x, partials);
    stats_kernel<<<1, 256, 0, stream>>>(partials, bn_gamma, bn_beta, stats);
    pool_partial_kernel<<<B_ * 32, 256, 0, stream>>>(x, stats, pp);
    mlp1_kernel<<<B_, 256, 0, stream>>>(pp, w1, b1, y1);
    mlp2_kernel<<<B_, 64, 0, stream>>>(y1, w2, b2, out);
}

// Round 10
// 254.212 us; speedup vs baseline: 1.0114x; 1.0006x over previous
//
#include <hip/hip_runtime.h>
#include <math.h>

#define B_ 32
#define P_ 2048
#define N_ 65536
#define K_ 16
#define L_ 8
#define F_ 64
#define KS_ 5
#define KS3_ 125
#define NC_ 40
#define H_ 256
#define EPS_ 1e-5f
#define QPB_ 128     // queries per block
#define SEGLEN_ 1024 // candidates per segment lane

// exact same fp expression everywhere (pinned fmaf order)
__device__ __forceinline__ float distf(float4 C, float nx, float ny, float nz, float qs) {
    return fmaf(C.x, nx, fmaf(C.y, ny, fmaf(C.z, nz, C.w))) + qs;
}

// packed-key insertion into sorted-ascending 16: pure min/max chain
__device__ __forceinline__ void insU(unsigned (&bu)[16], unsigned k) {
#pragma unroll
    for (int m = 0; m < 16; m++) {
        unsigned mn = min(bu[m], k);
        k = max(bu[m], k);
        bu[m] = mn;
    }
}

// exact (float,int) sorted insertion for the final reorder
__device__ __forceinline__ void insert16(float (&bd)[16], int (&bi)[16], float cd, int ci) {
#pragma unroll
    for (int m = 0; m < 16; m++) {
        bool sw = cd < bd[m];
        float td = sw ? bd[m] : cd;
        int   ti = sw ? bi[m] : ci;
        bd[m] = sw ? cd : bd[m];
        bi[m] = sw ? ci : bi[m];
        cd = td; ci = ti;
    }
}

// ---- Kernel 1: KNN + geometry, 2 segment-lanes per query ----
// Block = 128 queries x 2 segments (256 thr). Lane: seg = t&1, query = t>>1.
// Scan: top-16 per (query,seg) by packed key (21-bit dist prefix | 11-bit idx)
// over 1024 candidates; threshold = min(own bu[15], partner bu[15]) shared via
// ONE shfl_xor at each flush. Validity: any lane's 16th-of-seen >= union 16th
// (16th of a subset >= 16th of the superset), and if thr equals a top-16 key
// that key is already captured in the poster's bu (keys unique); so no true
// union-top-16 key is ever rejected. Depth-8 accept buffer (full when e7 holds
// a real key; real keys <= 0x7FFFFFFF). Both seg-lanes of a query read the
// same broadcast LDS address per iter (2 distinct addrs/wave = conflict-free).
// Merge: ONE bitonic round (reversed-shuffle half-cleaner + sort) -> both
// lanes hold the sorted union-top-16. Exact f32 distances recomputed for the
// 16 winners (stable (d,j) order), then cov/QR/dc geometry from LDS cloud.
// __launch_bounds__(256,4): VGPR cap 128 >= ~90 peak live -> no scratch spill
// (round-8 lesson: a tighter cap forced 226 MB/dispatch of spill traffic).
__global__ __launch_bounds__(256, 4) void knn_geom_kernel(const float* __restrict__ pos,
                                                          float* __restrict__ dcn) {
    __shared__ float4 cloud[P_];                 // 32 KB
    int b = blockIdx.x >> 4, tile = blockIdx.x & 15;
    int base = b * P_;
    int t = threadIdx.x;
    for (int j = t; j < P_; j += 256) {
        float x = pos[(base + j) * 3 + 0];
        float y = pos[(base + j) * 3 + 1];
        float z = pos[(base + j) * 3 + 2];
        cloud[j] = make_float4(x, y, z, x * x + y * y + z * z);
    }
    __syncthreads();

    int s = t & 1;                                // segment lane
    int il = tile * QPB_ + (t >> 1);              // this lane's query
    float4 Q = cloud[il];
    float nx = -2.f * Q.x, ny = -2.f * Q.y, nz = -2.f * Q.z, qs = Q.w;
    int il_self = (s == (il >> 10)) ? il : -1;    // only the owning seg excludes self

    unsigned bu[16];
#pragma unroll
    for (int m = 0; m < 16; m++) bu[m] = 0xFFFFFFFFu;
    unsigned e0 = ~0u, e1 = ~0u, e2 = ~0u, e3 = ~0u,
             e4 = ~0u, e5 = ~0u, e6 = ~0u, e7 = ~0u;
    unsigned thr = 0xFFFFFFFFu;

    int j0 = s << 10;
    float4 C0 = cloud[j0], C1 = cloud[j0 + 1];    // 2-ahead prefetch pipeline
    for (int jj = 0; jj < SEGLEN_; jj++) {
        float4 Cn = cloud[j0 | ((jj + 2) & 1023)];
        int j = j0 | jj;
        float d = distf(C0, nx, ny, nz, qs);
        unsigned key = (__float_as_uint(fmaxf(d, 0.f)) & 0xFFFFF800u) | (unsigned)j;
        bool acc = (key < thr) && (j != il_self);
        e7 = acc ? e6 : e7;
        e6 = acc ? e5 : e6;
        e5 = acc ? e4 : e5;
        e4 = acc ? e3 : e4;
        e3 = acc ? e2 : e3;
        e2 = acc ? e1 : e2;
        e1 = acc ? e0 : e1;
        e0 = acc ? key : e0;
        if (__any(e7 != 0xFFFFFFFFu)) {           // some lane buffered 8 accepts
            insU(bu, e7); insU(bu, e6); insU(bu, e5); insU(bu, e4);
            insU(bu, e3); insU(bu, e2); insU(bu, e1); insU(bu, e0);
            e0 = e1 = e2 = e3 = e4 = e5 = e6 = e7 = 0xFFFFFFFFu;
            unsigned t16 = bu[15];                // share with the partner seg-lane
            t16 = min(t16, (unsigned)__shfl_xor((int)t16, 1, 64));
            thr = min(thr, t16);
        }
        C0 = C1; C1 = Cn;
    }
    insU(bu, e7); insU(bu, e6); insU(bu, e5); insU(bu, e4);
    insU(bu, e3); insU(bu, e2); insU(bu, e1); insU(bu, e0);

    // ---- one bitonic merge round: both lanes -> sorted union-top-16 ----
    {
        unsigned o[16];
#pragma unroll
        for (int i = 0; i < 16; i++)
            o[i] = (unsigned)__shfl_xor((int)bu[15 - i], 1, 64);     // partner reversed
#pragma unroll
        for (int i = 0; i < 16; i++) bu[i] = min(bu[i], o[i]);       // half-cleaner
#pragma unroll
        for (int dd = 8; dd >= 1; dd >>= 1)                          // bitonic sort asc
#pragma unroll
            for (int k2 = 0; k2 < 16; k2 += 2 * dd)
#pragma unroll
                for (int i2 = k2; i2 < k2 + dd; i2++) {
                    unsigned mn = min(bu[i2], bu[i2 + dd]);
                    bu[i2 + dd] = max(bu[i2], bu[i2 + dd]);
                    bu[i2] = mn;
                }
    }

    // ---- exact reorder: recompute f32 distances, stable (d, j) ----
    float md[16]; int mi[16];
#pragma unroll
    for (int m = 0; m < 16; m++) { md[m] = INFINITY; mi[m] = 0; }
#pragma unroll
    for (int m = 0; m < 16; m++) {
        int j = bu[m] & 0x7FF;
        float4 Cm = cloud[j];
        insert16(md, mi, distf(Cm, nx, ny, nz, qs), j);
    }

    // ---- geometry: cov over L=8, 5x QR (LAPACK Householder), dc ----
    float px = Q.x, py = Q.y, pz = Q.z;
    float A[3][3];
    {
        float a00 = 0, a01 = 0, a02 = 0, a11 = 0, a12 = 0, a22 = 0;
#pragma unroll
        for (int l = 0; l < L_; l++) {
            float4 Cv = cloud[mi[l]];
            float ccx = Cv.x - px, ccy = Cv.y - py, ccz = Cv.z - pz;
            a00 += ccx * ccx; a01 += ccx * ccy; a02 += ccx * ccz;
            a11 += ccy * ccy; a12 += ccy * ccz; a22 += ccz * ccz;
        }
        A[0][0] = a00; A[0][1] = a01; A[0][2] = a02;
        A[1][0] = a01; A[1][1] = a11; A[1][2] = a12;
        A[2][0] = a02; A[2][1] = a12; A[2][2] = a22;
    }
    float Vt[3][3] = {{1.f, 0.f, 0.f}, {0.f, 1.f, 0.f}, {0.f, 0.f, 1.f}};

    for (int it = 0; it < 5; it++) {
        float M00 = A[0][0], M01 = A[0][1], M02 = A[0][2];
        float M10 = A[1][0], M11 = A[1][1], M12 = A[1][2];
        float M20 = A[2][0], M21 = A[2][1], M22 = A[2][2];
        float tau0 = 0.f, v1 = 0.f, v2 = 0.f;
        float xn2 = M10 * M10 + M20 * M20;
        if (xn2 != 0.f) {
            float beta = -copysignf(sqrtf(M00 * M00 + xn2), M00);
            tau0 = (beta - M00) / beta;
            float inv = 1.f / (M00 - beta);
            v1 = M10 * inv; v2 = M20 * inv;
            float sc;
            sc = tau0 * (M01 + v1 * M11 + v2 * M21); M01 -= sc; M11 -= v1 * sc; M21 -= v2 * sc;
            sc = tau0 * (M02 + v1 * M12 + v2 * M22); M02 -= sc; M12 -= v1 * sc; M22 -= v2 * sc;
            M00 = beta;
        }
        float tau1 = 0.f, u2 = 0.f;
        if (M21 != 0.f) {
            float beta1 = -copysignf(sqrtf(M11 * M11 + M21 * M21), M11);
            tau1 = (beta1 - M11) / beta1;
            u2 = M21 / (M11 - beta1);
            float sc = tau1 * (M12 + u2 * M22); M12 -= sc; M22 -= u2 * sc;
            M11 = beta1;
        }
        float h11 = 1.f - tau1, h12 = -tau1 * u2, h22 = 1.f - tau1 * u2 * u2;
        float Qm[3][3];
        Qm[0][0] = 1.f - tau0;
        Qm[1][0] = -v1 * tau0;
        Qm[2][0] = -v2 * tau0;
        float t1 = tau0 * (v1 * h11 + v2 * h12);
        Qm[0][1] = -t1;
        Qm[1][1] = h11 - v1 * t1;
        Qm[2][1] = h12 - v2 * t1;
        float t2 = tau0 * (v1 * h12 + v2 * h22);
        Qm[0][2] = -t2;
        Qm[1][2] = h12 - v1 * t2;
        Qm[2][2] = h22 - v2 * t2;
        A[0][0] = M00 * Qm[0][0] + M01 * Qm[1][0] + M02 * Qm[2][0];
        A[0][1] = M00 * Qm[0][1] + M01 * Qm[1][1] + M02 * Qm[2][1];
        A[0][2] = M00 * Qm[0][2] + M01 * Qm[1][2] + M02 * Qm[2][2];
        A[1][0] = M11 * Qm[1][0] + M12 * Qm[2][0];
        A[1][1] = M11 * Qm[1][1] + M12 * Qm[2][1];
        A[1][2] = M11 * Qm[1][2] + M12 * Qm[2][2];
        A[2][0] = M22 * Qm[2][0];
        A[2][1] = M22 * Qm[2][1];
        A[2][2] = M22 * Qm[2][2];
        float nv[3][3];
#pragma unroll
        for (int r = 0; r < 3; r++)
#pragma unroll
            for (int cc = 0; cc < 3; cc++)
                nv[r][cc] = Vt[r][0] * Qm[0][cc] + Vt[r][1] * Qm[1][cc] + Vt[r][2] * Qm[2][cc];
#pragma unroll
        for (int r = 0; r < 3; r++)
#pragma unroll
            for (int cc = 0; cc < 3; cc++) Vt[r][cc] = nv[r][cc];
    }

    // pass B: z-column sum + abs-max (recompute c from LDS)
    float s2 = 0.f, mx01 = 0.f, mx2 = 0.f;
#pragma unroll
    for (int k = 0; k < K_; k++) {
        float4 Cv = cloud[mi[k]];
        float ccx = Cv.x - px, ccy = Cv.y - py, ccz = Cv.z - pz;
        float d0 = ccx * Vt[0][0] + ccy * Vt[1][0] + ccz * Vt[2][0];
        float d1 = ccx * Vt[0][1] + ccy * Vt[1][1] + ccz * Vt[2][1];
        float d2 = ccx * Vt[0][2] + ccy * Vt[1][2] + ccz * Vt[2][2];
        s2 += d2;
        mx01 = fmaxf(mx01, fmaxf(fabsf(d0), fabsf(d1)));
        mx2  = fmaxf(mx2, fabsf(d2));
    }
    float sg = (s2 > 0.f) ? 1.f : ((s2 < 0.f) ? -1.f : 0.f);
    float mx = fmaxf(mx01, (sg == 0.f) ? 0.f : mx2);
    float hs = 0.5f / mx;

    // pass C: project, normalize, write; the two seg-lanes split the 4 groups
    {
        int i = base + il;
        float4* row = (float4*)(dcn + (size_t)i * 48);
#pragma unroll
        for (int gg = 0; gg < 2; gg++) {
            int g = s * 2 + gg;
            float v[12];
#pragma unroll
            for (int kk = 0; kk < 4; kk++) {
                int k = g * 4 + kk;
                float4 Cv = cloud[mi[k]];
                float ccx = Cv.x - px, ccy = Cv.y - py, ccz = Cv.z - pz;
                float d0 = ccx * Vt[0][0] + ccy * Vt[1][0] + ccz * Vt[2][0];
                float d1 = ccx * Vt[0][1] + ccy * Vt[1][1] + ccz * Vt[2][1];
                float d2 = (ccx * Vt[0][2] + ccy * Vt[1][2] + ccz * Vt[2][2]) * sg;
                v[kk * 3 + 0] = d0 * hs + 0.5f;
                v[kk * 3 + 1] = d1 * hs + 0.5f;
                v[kk * 3 + 2] = d2 * hs + 0.5f;
            }
#pragma unroll
            for (int r = 0; r < 3; r++)
                row[g * 3 + r] = make_float4(v[r * 4 + 0], v[r * 4 + 1],
                                             v[r * 4 + 2], v[r * 4 + 3]);
        }
    }
}

// ---------- Kernel 2: trilinear spline gather + out_nondir + BN partials -----
__global__ __launch_bounds__(256) void spline_kernel(const float* __restrict__ dcn,
                                                     const float* __restrict__ w_spline,
                                                     const float* __restrict__ w_root,
                                                     const float* __restrict__ b_spline,
                                                     float* __restrict__ x,
                                                     float* __restrict__ partials) {
    __shared__ float ws_t[F_ * KS3_];   // [f][cell], 32000 B
    __shared__ float red[4][64];
    {
        int f = threadIdx.x & 63;
        for (int c = threadIdx.x >> 6; c < KS3_; c += 4)
            ws_t[f * KS3_ + c] = w_spline[c * 64 + f];
    }
    __syncthreads();
    int wave = threadIdx.x >> 6, f = threadIdx.x & 63;
    const float* wbase = &ws_t[f * KS3_];
    float wr = w_root[f] + b_spline[f];
    float s1 = 0.f, s2 = 0.f;
    for (int p = 0; p < 16; p++) {
        int i = blockIdx.x * 64 + wave * 16 + p;
        const float4* row = (const float4*)(dcn + (size_t)i * 48);
        float pr[48];
#pragma unroll
        for (int m = 0; m < 12; m++) {
            float4 v = row[m];
            pr[m * 4 + 0] = v.x; pr[m * 4 + 1] = v.y;
            pr[m * 4 + 2] = v.z; pr[m * 4 + 3] = v.w;
        }
        float acc = 0.f;
#pragma unroll
        for (int k = 0; k < K_; k++) {
            float p0 = pr[k * 3 + 0] * 4.f;
            float p1 = pr[k * 3 + 1] * 4.f;
            float p2 = pr[k * 3 + 2] * 4.f;
            float i0 = fminf(fmaxf(floorf(p0), 0.f), 3.f);
            float i1 = fminf(fmaxf(floorf(p1), 0.f), 3.f);
            float i2 = fminf(fmaxf(floorf(p2), 0.f), 3.f);
            float f0 = p0 - i0, f1 = p1 - i1, f2 = p2 - i2;
            float g0 = 1.f - f0, g1 = 1.f - f1, g2 = 1.f - f2;
            int c = (int)fmaf(i2, 25.f, fmaf(i1, 5.f, i0));
            const float* wp = wbase + c;
            float a0 = wp[0],  a1 = wp[1];
            float b0 = wp[5],  b1v = wp[6];
            float c0 = wp[25], c1 = wp[26];
            float d0 = wp[30], d1 = wp[31];
            float wA = g1 * g2, wB = f1 * g2, wC = g1 * f2, wD = f1 * f2;
            acc = fmaf(wA, fmaf(f0, a1, g0 * a0), acc);
            acc = fmaf(wB, fmaf(f0, b1v, g0 * b0), acc);
            acc = fmaf(wC, fmaf(f0, c1, g0 * c0), acc);
            acc = fmaf(wD, fmaf(f0, d1, g0 * d0), acc);
        }
        float xv = acc * (1.f / 16.f) + wr;
        x[(size_t)i * 64 + f] = xv;
        s1 += xv; s2 += xv * xv;
    }
    red[wave][f] = s1; __syncthreads();
    if (threadIdx.x < 64)
        partials[blockIdx.x * 128 + f] = red[0][f] + red[1][f] + red[2][f] + red[3][f];
    __syncthreads();
    red[wave][f] = s2; __syncthreads();
    if (threadIdx.x < 64)
        partials[blockIdx.x * 128 + 64 + f] = red[0][f] + red[1][f] + red[2][f] + red[3][f];
}

// ----------------------- Kernel 3: BN stats finalize -------------------------
__global__ __launch_bounds__(256) void stats_kernel(const float* __restrict__ partials,
                                                    const float* __restrict__ gamma,
                                                    const float* __restrict__ beta,
                                                    float* __restrict__ stats) {
    __shared__ double red1[256], red2[256];
    int t = threadIdx.x;
    int f = t & 63, g = t >> 6;
    double a0 = 0, a1 = 0, a2 = 0, a3 = 0, q0 = 0, q1 = 0, q2 = 0, q3 = 0;
    for (int b2 = g; b2 < 1024; b2 += 16) {
        a0 += (double)partials[(b2     ) * 128 + f];
        q0 += (double)partials[(b2     ) * 128 + 64 + f];
        a1 += (double)partials[(b2 +  4) * 128 + f];
        q1 += (double)partials[(b2 +  4) * 128 + 64 + f];
        a2 += (double)partials[(b2 +  8) * 128 + f];
        q2 += (double)partials[(b2 +  8) * 128 + 64 + f];
        a3 += (double)partials[(b2 + 12) * 128 + f];
        q3 += (double)partials[(b2 + 12) * 128 + 64 + f];
    }
    red1[t] = (a0 + a1) + (a2 + a3);
    red2[t] = (q0 + q1) + (q2 + q3);
    __syncthreads();
    if (t < 64) {
        double S1 = red1[t] + red1[t + 64] + red1[t + 128] + red1[t + 192];
        double S2 = red2[t] + red2[t + 64] + red2[t + 128] + red2[t + 192];
        double mu = S1 / (double)N_;
        double var = S2 / (double)N_ - mu * mu;
        double scale = (double)gamma[t] / sqrt(var + (double)EPS_);
        double shift = (double)beta[t] - mu * scale;
        stats[t] = (float)scale;
        stats[64 + t] = (float)shift;
    }
}

// -------------- Kernel 4: sigmoid + per-batch-chunk partial pool -------------
__global__ __launch_bounds__(256) void pool_partial_kernel(const float* __restrict__ x,
                                                           const float* __restrict__ stats,
                                                           float* __restrict__ pp) {
    __shared__ float red[4][64];
    int blk = blockIdx.x;            // 32 batches * 32 chunks of 64 rows
    int b = blk >> 5, ch = blk & 31;
    int f = threadIdx.x & 63, w = threadIdx.x >> 6;
    float scale = stats[f], shift = stats[64 + f];
    float acc = 0.f;
    int row0 = b * P_ + ch * 64;
    for (int r = w; r < 64; r += 4) {
        float v = x[(size_t)(row0 + r) * 64 + f];
        float t = fmaf(v, scale, shift);
        acc += __fdividef(1.f, 1.f + __expf(-t));
    }
    red[w][f] = acc; __syncthreads();
    if (threadIdx.x < 64) pp[blk * 64 + f] = red[0][f] + red[1][f] + red[2][f] + red[3][f];
}

// ------------------ Kernel 5: batch means + GEMM1 + ELU ----------------------
__global__ __launch_bounds__(256) void mlp1_kernel(const float* __restrict__ pp,
                                                   const float* __restrict__ w1,
                                                   const float* __restrict__ b1,
                                                   float* __restrict__ y1) {
    __shared__ float ssy[64];
    int b = blockIdx.x, t = threadIdx.x;
    if (t < 64) {
        float s = 0.f;
#pragma unroll
        for (int g = 0; g < 32; g++) s += pp[(b * 32 + g) * 64 + t];
        ssy[t] = s * (1.f / 2048.f);
    }
    __syncthreads();
    float acc = b1[t];
#pragma unroll 8
    for (int c = 0; c < F_; c++) acc = fmaf(ssy[c], w1[c * 256 + t], acc);
    y1[b * 256 + t] = acc > 0.f ? acc : expm1f(acc);
}

// ------------------ Kernel 6: GEMM2 + log_softmax (wave-wide) ----------------
__global__ __launch_bounds__(64) void mlp2_kernel(const float* __restrict__ y1,
                                                  const float* __restrict__ w2,
                                                  const float* __restrict__ b2,
                                                  float* __restrict__ out) {
    int b = blockIdx.x, j = threadIdx.x;
    float acc = -INFINITY;
    if (j < NC_) {
        acc = b2[j];
#pragma unroll 8
        for (int c = 0; c < H_; c++) acc = fmaf(y1[b * 256 + c], w2[c * 40 + j], acc);
    }
    float m = acc;
#pragma unroll
    for (int o = 32; o > 0; o >>= 1) m = fmaxf(m, __shfl_xor(m, o, 64));
    float e = (j < NC_) ? expf(acc - m) : 0.f;
    float s = e;
#pragma unroll
    for (int o = 32; o > 0; o >>= 1) s += __shfl_xor(s, o, 64);
    if (j < NC_) out[b * NC_ + j] = acc - m - logf(s);
}

extern "C" void kernel_launch(void* const* d_in, const int* in_sizes, int n_in,
                              void* d_out, int out_size, void* d_ws, size_t ws_size,
                              hipStream_t stream) {
    const float* pos      = (const float*)d_in[0];
    const float* w_spline = (const float*)d_in[2];
    const float* w_root   = (const float*)d_in[3];
    const float* b_spline = (const float*)d_in[4];
    const float* bn_gamma = (const float*)d_in[5];
    const float* bn_beta  = (const float*)d_in[6];
    const float* w1       = (const float*)d_in[7];
    const float* b1       = (const float*)d_in[8];
    const float* w2       = (const float*)d_in[9];
    const float* b2       = (const float*)d_in[10];
    float* out = (float*)d_out;

    char* ws = (char*)d_ws;
    float* dcn      = (float*)(ws + 0);                    // 12 MB
    float* x        = (float*)(ws + (12u << 20));          // 16 MB
    float* partials = (float*)(ws + (28u << 20));          // 512 KB
    float* stats    = (float*)(ws + (28u << 20) + (512u << 10));               // 4 KB slot
    float* pp       = (float*)(ws + (28u << 20) + (512u << 10) + 4096);        // 256 KB
    float* y1       = (float*)(ws + (28u << 20) + (512u << 10) + 4096 + (256u << 10)); // 32 KB

    knn_geom_kernel<<<B_ * 16, 256, 0, stream>>>(pos, dcn);
    spline_kernel<<<N_ / 64, 256, 0, stream>>>(dcn, w_spline, w_root, b_spline, x, partials);
    stats_kernel<<<1, 256, 0, stream>>>(partials, bn_gamma, bn_beta, stats);
    pool_partial_kernel<<<B_ * 32, 256, 0, stream>>>(x, stats, pp);
    mlp1_kernel<<<B_, 256, 0, stream>>>(pp, w1, b1, y1);
    mlp2_kernel<<<B_, 64, 0, stream>>>(y1, w2, b2, out);
}

// Round 11
// 216.753 us; speedup vs baseline: 1.1862x; 1.1728x over previous
//
#include <hip/hip_runtime.h>
#include <math.h>

#define B_ 32
#define P_ 2048
#define N_ 65536
#define K_ 16
#define L_ 8
#define F_ 64
#define KS_ 5
#define KS3_ 125
#define NC_ 40
#define H_ 256
#define EPS_ 1e-5f
#define QPB_ 64      // queries per block
#define SEG_ 4       // segment lanes per query
#define SEGLEN_ 512  // candidates per segment lane

// exact same fp expression everywhere (pinned fmaf order)
__device__ __forceinline__ float distf(float4 C, float nx, float ny, float nz, float qs) {
    return fmaf(C.x, nx, fmaf(C.y, ny, fmaf(C.z, nz, C.w))) + qs;
}

// compare-exchange (ascending): 2 inst
#define CES(a, b) { unsigned _mn = min(a, b); b = max(a, b); a = _mn; }

// ascending bitonic merge of a bitonic 16-sequence (32 CE, fully static)
__device__ __forceinline__ void bitmerge16(unsigned (&a)[16]) {
#pragma unroll
    for (int dd = 8; dd >= 1; dd >>= 1)
#pragma unroll
        for (int k2 = 0; k2 < 16; k2 += 2 * dd)
#pragma unroll
            for (int i2 = k2; i2 < k2 + dd; i2++)
                CES(a[i2], a[i2 + dd])
}

// Flush 8 buffered keys into sorted-ascending bu[16], Batcher-style:
// sort-8 (19 CE) + half-cleaner vs bu (8 CE) + bitonic merge (32 CE)
// == identical result to 8 sequential sorted-insertions (16 smallest of
// bu ∪ {e0..e7}, sorted), at ~half the instructions.
__device__ __forceinline__ void flush8(unsigned (&bu)[16],
                                       unsigned& e0, unsigned& e1, unsigned& e2, unsigned& e3,
                                       unsigned& e4, unsigned& e5, unsigned& e6, unsigned& e7,
                                       unsigned& thr) {
    // Batcher odd-even mergesort of 8
    CES(e0, e1) CES(e2, e3) CES(e4, e5) CES(e6, e7)
    CES(e0, e2) CES(e1, e3) CES(e4, e6) CES(e5, e7)
    CES(e1, e2) CES(e5, e6)
    CES(e0, e4) CES(e1, e5) CES(e2, e6) CES(e3, e7)
    CES(e2, e4) CES(e3, e5)
    CES(e1, e2) CES(e3, e4) CES(e5, e6)
    // S = [bu asc | INF x8, e7..e0] is bitonic(32); half-clean (i<8 no-ops)
    CES(bu[8],  e7) CES(bu[9],  e6) CES(bu[10], e5) CES(bu[11], e4)
    CES(bu[12], e3) CES(bu[13], e2) CES(bu[14], e1) CES(bu[15], e0)
    bitmerge16(bu);   // low half is bitonic + holds the 16 smallest
    e0 = e1 = e2 = e3 = e4 = e5 = e6 = e7 = 0xFFFFFFFFu;
    unsigned t16 = bu[15];          // share threshold across the 4 seg-lanes
    t16 = min(t16, (unsigned)__shfl_xor((int)t16, 1, 64));
    t16 = min(t16, (unsigned)__shfl_xor((int)t16, 2, 64));
    thr = min(thr, t16);
}

// exact (float,int) sorted insertion for the final reorder
__device__ __forceinline__ void insert16(float (&bd)[16], int (&bi)[16], float cd, int ci) {
#pragma unroll
    for (int m = 0; m < 16; m++) {
        bool sw = cd < bd[m];
        float td = sw ? bd[m] : cd;
        int   ti = sw ? bi[m] : ci;
        bd[m] = sw ? cd : bd[m];
        bi[m] = sw ? ci : bi[m];
        cd = td; ci = ti;
    }
}

// ---- Kernel 1: KNN + geometry, 4 segment-lanes per query ----
// Block = 64 queries x 4 segments (256 thr). Lane: s = t&3, query = t>>2
// (4 consecutive lanes per query -> shfl_xor 1,2 stay in-group).
// Scan: top-16 per (query,seg) by packed key (21-bit dist prefix | 11-bit
// idx) over 512 candidates, visited in rotated order (jj+2s)&511 so the 4
// distinct LDS addresses per read hit disjoint bank quads (conflict-free).
// Unroll-4 with flush check once per block: depth-8 buffer, trigger when any
// lane has >=5 buffered (e4 real) -> max 4+4=8 buffered, no overflow.
// Threshold = 4-lane min of bu[15] at each flush (subset 16th >= union 16th,
// keys unique -> strict < exact): no true union-top-16 key ever rejected.
// Merge: 2 bitonic rounds -> all 4 lanes hold sorted union-top-16. Exact f32
// reorder (stable (d,j)), then cov/QR/dc geometry from LDS cloud.
// __launch_bounds__(256,4): VGPR cap 128 >= ~90 peak live -> no spill
// (round-8 lesson: tighter cap = 226 MB/dispatch spill traffic).
__global__ __launch_bounds__(256, 4) void knn_geom_kernel(const float* __restrict__ pos,
                                                          float* __restrict__ dcn) {
    __shared__ float4 cloud[P_];                 // 32 KB
    int b = blockIdx.x >> 5, tile = blockIdx.x & 31;
    int base = b * P_;
    int t = threadIdx.x;
    for (int j = t; j < P_; j += 256) {
        float x = pos[(base + j) * 3 + 0];
        float y = pos[(base + j) * 3 + 1];
        float z = pos[(base + j) * 3 + 2];
        cloud[j] = make_float4(x, y, z, x * x + y * y + z * z);
    }
    __syncthreads();

    int s = t & 3;                                // segment lane
    int il = tile * QPB_ + (t >> 2);              // this lane's query
    float4 Q = cloud[il];
    float nx = -2.f * Q.x, ny = -2.f * Q.y, nz = -2.f * Q.z, qs = Q.w;
    int il_self = (s == (il >> 9)) ? il : -1;     // only the owning seg excludes self

    unsigned bu[16];
#pragma unroll
    for (int m = 0; m < 16; m++) bu[m] = 0xFFFFFFFFu;
    unsigned e0 = ~0u, e1 = ~0u, e2 = ~0u, e3 = ~0u,
             e4 = ~0u, e5 = ~0u, e6 = ~0u, e7 = ~0u;
    unsigned thr = 0xFFFFFFFFu;

    int j0 = s << 9, off = s << 1;                // rotation: banks 4jj+8s

#define VISIT(Cv, JJ) {                                                          \
        int j_ = j0 | (((JJ) + off) & 511);                                      \
        float d_ = distf(Cv, nx, ny, nz, qs);                                    \
        unsigned key_ = (__float_as_uint(fmaxf(d_, 0.f)) & 0xFFFFF800u)          \
                        | (unsigned)j_;                                          \
        bool a_ = (key_ < thr) && (j_ != il_self);                               \
        e7 = a_ ? e6 : e7;  e6 = a_ ? e5 : e6;  e5 = a_ ? e4 : e5;               \
        e4 = a_ ? e3 : e4;  e3 = a_ ? e2 : e3;  e2 = a_ ? e1 : e2;               \
        e1 = a_ ? e0 : e1;  e0 = a_ ? key_ : e0;                                 \
    }

    float4 c0 = cloud[j0 | ((off + 0) & 511)];
    float4 c1 = cloud[j0 | ((off + 1) & 511)];
    float4 c2 = cloud[j0 | ((off + 2) & 511)];
    float4 c3 = cloud[j0 | ((off + 3) & 511)];
    for (int jj = 0; jj < SEGLEN_; jj += 4) {
        float4 n0 = cloud[j0 | ((jj + off + 4) & 511)];
        float4 n1 = cloud[j0 | ((jj + off + 5) & 511)];
        float4 n2 = cloud[j0 | ((jj + off + 6) & 511)];
        float4 n3 = cloud[j0 | ((jj + off + 7) & 511)];
        VISIT(c0, jj + 0)
        VISIT(c1, jj + 1)
        VISIT(c2, jj + 2)
        VISIT(c3, jj + 3)
        if (__any(e4 != 0xFFFFFFFFu))             // some lane buffered >= 5
            flush8(bu, e0, e1, e2, e3, e4, e5, e6, e7, thr);
        c0 = n0; c1 = n1; c2 = n2; c3 = n3;
    }
    flush8(bu, e0, e1, e2, e3, e4, e5, e6, e7, thr);   // drain (<= 4 left)
#undef VISIT

    // ---- 2 bitonic rounds: all 4 seg-lanes -> sorted union-top-16 ----
#pragma unroll
    for (int mask = 1; mask <= 2; mask <<= 1) {
        unsigned o[16];
#pragma unroll
        for (int i = 0; i < 16; i++)
            o[i] = (unsigned)__shfl_xor((int)bu[15 - i], mask, 64);  // partner reversed
#pragma unroll
        for (int i = 0; i < 16; i++) bu[i] = min(bu[i], o[i]);       // half-cleaner
        bitmerge16(bu);
    }

    // ---- exact reorder: recompute f32 distances, stable (d, j) ----
    float md[16]; int mi[16];
#pragma unroll
    for (int m = 0; m < 16; m++) { md[m] = INFINITY; mi[m] = 0; }
#pragma unroll
    for (int m = 0; m < 16; m++) {
        int j = bu[m] & 0x7FF;
        float4 Cm = cloud[j];
        insert16(md, mi, distf(Cm, nx, ny, nz, qs), j);
    }

    // ---- geometry: cov over L=8, 5x QR (LAPACK Householder), dc ----
    float px = Q.x, py = Q.y, pz = Q.z;
    float A[3][3];
    {
        float a00 = 0, a01 = 0, a02 = 0, a11 = 0, a12 = 0, a22 = 0;
#pragma unroll
        for (int l = 0; l < L_; l++) {
            float4 Cv = cloud[mi[l]];
            float ccx = Cv.x - px, ccy = Cv.y - py, ccz = Cv.z - pz;
            a00 += ccx * ccx; a01 += ccx * ccy; a02 += ccx * ccz;
            a11 += ccy * ccy; a12 += ccy * ccz; a22 += ccz * ccz;
        }
        A[0][0] = a00; A[0][1] = a01; A[0][2] = a02;
        A[1][0] = a01; A[1][1] = a11; A[1][2] = a12;
        A[2][0] = a02; A[2][1] = a12; A[2][2] = a22;
    }
    float Vt[3][3] = {{1.f, 0.f, 0.f}, {0.f, 1.f, 0.f}, {0.f, 0.f, 1.f}};

    for (int it = 0; it < 5; it++) {
        float M00 = A[0][0], M01 = A[0][1], M02 = A[0][2];
        float M10 = A[1][0], M11 = A[1][1], M12 = A[1][2];
        float M20 = A[2][0], M21 = A[2][1], M22 = A[2][2];
        float tau0 = 0.f, v1 = 0.f, v2 = 0.f;
        float xn2 = M10 * M10 + M20 * M20;
        if (xn2 != 0.f) {
            float beta = -copysignf(sqrtf(M00 * M00 + xn2), M00);
            tau0 = (beta - M00) / beta;
            float inv = 1.f / (M00 - beta);
            v1 = M10 * inv; v2 = M20 * inv;
            float sc;
            sc = tau0 * (M01 + v1 * M11 + v2 * M21); M01 -= sc; M11 -= v1 * sc; M21 -= v2 * sc;
            sc = tau0 * (M02 + v1 * M12 + v2 * M22); M02 -= sc; M12 -= v1 * sc; M22 -= v2 * sc;
            M00 = beta;
        }
        float tau1 = 0.f, u2 = 0.f;
        if (M21 != 0.f) {
            float beta1 = -copysignf(sqrtf(M11 * M11 + M21 * M21), M11);
            tau1 = (beta1 - M11) / beta1;
            u2 = M21 / (M11 - beta1);
            float sc = tau1 * (M12 + u2 * M22); M12 -= sc; M22 -= u2 * sc;
            M11 = beta1;
        }
        float h11 = 1.f - tau1, h12 = -tau1 * u2, h22 = 1.f - tau1 * u2 * u2;
        float Qm[3][3];
        Qm[0][0] = 1.f - tau0;
        Qm[1][0] = -v1 * tau0;
        Qm[2][0] = -v2 * tau0;
        float t1 = tau0 * (v1 * h11 + v2 * h12);
        Qm[0][1] = -t1;
        Qm[1][1] = h11 - v1 * t1;
        Qm[2][1] = h12 - v2 * t1;
        float t2 = tau0 * (v1 * h12 + v2 * h22);
        Qm[0][2] = -t2;
        Qm[1][2] = h12 - v1 * t2;
        Qm[2][2] = h22 - v2 * t2;
        A[0][0] = M00 * Qm[0][0] + M01 * Qm[1][0] + M02 * Qm[2][0];
        A[0][1] = M00 * Qm[0][1] + M01 * Qm[1][1] + M02 * Qm[2][1];
        A[0][2] = M00 * Qm[0][2] + M01 * Qm[1][2] + M02 * Qm[2][2];
        A[1][0] = M11 * Qm[1][0] + M12 * Qm[2][0];
        A[1][1] = M11 * Qm[1][1] + M12 * Qm[2][1];
        A[1][2] = M11 * Qm[1][2] + M12 * Qm[2][2];
        A[2][0] = M22 * Qm[2][0];
        A[2][1] = M22 * Qm[2][1];
        A[2][2] = M22 * Qm[2][2];
        float nv[3][3];
#pragma unroll
        for (int r = 0; r < 3; r++)
#pragma unroll
            for (int cc = 0; cc < 3; cc++)
                nv[r][cc] = Vt[r][0] * Qm[0][cc] + Vt[r][1] * Qm[1][cc] + Vt[r][2] * Qm[2][cc];
#pragma unroll
        for (int r = 0; r < 3; r++)
#pragma unroll
            for (int cc = 0; cc < 3; cc++) Vt[r][cc] = nv[r][cc];
    }

    // pass B: z-column sum + abs-max (recompute c from LDS)
    float s2 = 0.f, mx01 = 0.f, mx2 = 0.f;
#pragma unroll
    for (int k = 0; k < K_; k++) {
        float4 Cv = cloud[mi[k]];
        float ccx = Cv.x - px, ccy = Cv.y - py, ccz = Cv.z - pz;
        float d0 = ccx * Vt[0][0] + ccy * Vt[1][0] + ccz * Vt[2][0];
        float d1 = ccx * Vt[0][1] + ccy * Vt[1][1] + ccz * Vt[2][1];
        float d2 = ccx * Vt[0][2] + ccy * Vt[1][2] + ccz * Vt[2][2];
        s2 += d2;
        mx01 = fmaxf(mx01, fmaxf(fabsf(d0), fabsf(d1)));
        mx2  = fmaxf(mx2, fabsf(d2));
    }
    float sg = (s2 > 0.f) ? 1.f : ((s2 < 0.f) ? -1.f : 0.f);
    float mx = fmaxf(mx01, (sg == 0.f) ? 0.f : mx2);
    float hs = 0.5f / mx;

    // pass C: project, normalize, write; the 4 seg-lanes split the 4 groups
    {
        int i = base + il;
        float4* row = (float4*)(dcn + (size_t)i * 48);
        int g = s;
        float v[12];
#pragma unroll
        for (int kk = 0; kk < 4; kk++) {
            int k = g * 4 + kk;
            float4 Cv = cloud[mi[k]];
            float ccx = Cv.x - px, ccy = Cv.y - py, ccz = Cv.z - pz;
            float d0 = ccx * Vt[0][0] + ccy * Vt[1][0] + ccz * Vt[2][0];
            float d1 = ccx * Vt[0][1] + ccy * Vt[1][1] + ccz * Vt[2][1];
            float d2 = (ccx * Vt[0][2] + ccy * Vt[1][2] + ccz * Vt[2][2]) * sg;
            v[kk * 3 + 0] = d0 * hs + 0.5f;
            v[kk * 3 + 1] = d1 * hs + 0.5f;
            v[kk * 3 + 2] = d2 * hs + 0.5f;
        }
#pragma unroll
        for (int r = 0; r < 3; r++)
            row[g * 3 + r] = make_float4(v[r * 4 + 0], v[r * 4 + 1],
                                         v[r * 4 + 2], v[r * 4 + 3]);
    }
}

// ---------- Kernel 2: trilinear spline gather + out_nondir + BN partials -----
__global__ __launch_bounds__(256) void spline_kernel(const float* __restrict__ dcn,
                                                     const float* __restrict__ w_spline,
                                                     const float* __restrict__ w_root,
                                                     const float* __restrict__ b_spline,
                                                     float* __restrict__ x,
                                                     float* __restrict__ partials) {
    __shared__ float ws_t[F_ * KS3_];   // [f][cell], 32000 B
    __shared__ float red[4][64];
    {
        int f = threadIdx.x & 63;
        for (int c = threadIdx.x >> 6; c < KS3_; c += 4)
            ws_t[f * KS3_ + c] = w_spline[c * 64 + f];
    }
    __syncthreads();
    int wave = threadIdx.x >> 6, f = threadIdx.x & 63;
    const float* wbase = &ws_t[f * KS3_];
    float wr = w_root[f] + b_spline[f];
    float s1 = 0.f, s2 = 0.f;
    for (int p = 0; p < 16; p++) {
        int i = blockIdx.x * 64 + wave * 16 + p;
        const float4* row = (const float4*)(dcn + (size_t)i * 48);
        float pr[48];
#pragma unroll
        for (int m = 0; m < 12; m++) {
            float4 v = row[m];
            pr[m * 4 + 0] = v.x; pr[m * 4 + 1] = v.y;
            pr[m * 4 + 2] = v.z; pr[m * 4 + 3] = v.w;
        }
        float acc = 0.f;
#pragma unroll
        for (int k = 0; k < K_; k++) {
            float p0 = pr[k * 3 + 0] * 4.f;
            float p1 = pr[k * 3 + 1] * 4.f;
            float p2 = pr[k * 3 + 2] * 4.f;
            float i0 = fminf(fmaxf(floorf(p0), 0.f), 3.f);
            float i1 = fminf(fmaxf(floorf(p1), 0.f), 3.f);
            float i2 = fminf(fmaxf(floorf(p2), 0.f), 3.f);
            float f0 = p0 - i0, f1 = p1 - i1, f2 = p2 - i2;
            float g0 = 1.f - f0, g1 = 1.f - f1, g2 = 1.f - f2;
            int c = (int)fmaf(i2, 25.f, fmaf(i1, 5.f, i0));
            const float* wp = wbase + c;
            float a0 = wp[0],  a1 = wp[1];
            float b0 = wp[5],  b1v = wp[6];
            float c0 = wp[25], c1 = wp[26];
            float d0 = wp[30], d1 = wp[31];
            float wA = g1 * g2, wB = f1 * g2, wC = g1 * f2, wD = f1 * f2;
            acc = fmaf(wA, fmaf(f0, a1, g0 * a0), acc);
            acc = fmaf(wB, fmaf(f0, b1v, g0 * b0), acc);
            acc = fmaf(wC, fmaf(f0, c1, g0 * c0), acc);
            acc = fmaf(wD, fmaf(f0, d1, g0 * d0), acc);
        }
        float xv = acc * (1.f / 16.f) + wr;
        x[(size_t)i * 64 + f] = xv;
        s1 += xv; s2 += xv * xv;
    }
    red[wave][f] = s1; __syncthreads();
    if (threadIdx.x < 64)
        partials[blockIdx.x * 128 + f] = red[0][f] + red[1][f] + red[2][f] + red[3][f];
    __syncthreads();
    red[wave][f] = s2; __syncthreads();
    if (threadIdx.x < 64)
        partials[blockIdx.x * 128 + 64 + f] = red[0][f] + red[1][f] + red[2][f] + red[3][f];
}

// ----------------------- Kernel 3: BN stats finalize -------------------------
__global__ __launch_bounds__(256) void stats_kernel(const float* __restrict__ partials,
                                                    const float* __restrict__ gamma,
                                                    const float* __restrict__ beta,
                                                    float* __restrict__ stats) {
    __shared__ double red1[256], red2[256];
    int t = threadIdx.x;
    int f = t & 63, g = t >> 6;
    double a0 = 0, a1 = 0, a2 = 0, a3 = 0, q0 = 0, q1 = 0, q2 = 0, q3 = 0;
    for (int b2 = g; b2 < 1024; b2 += 16) {
        a0 += (double)partials[(b2     ) * 128 + f];
        q0 += (double)partials[(b2     ) * 128 + 64 + f];
        a1 += (double)partials[(b2 +  4) * 128 + f];
        q1 += (double)partials[(b2 +  4) * 128 + 64 + f];
        a2 += (double)partials[(b2 +  8) * 128 + f];
        q2 += (double)partials[(b2 +  8) * 128 + 64 + f];
        a3 += (double)partials[(b2 + 12) * 128 + f];
        q3 += (double)partials[(b2 + 12) * 128 + 64 + f];
    }
    red1[t] = (a0 + a1) + (a2 + a3);
    red2[t] = (q0 + q1) + (q2 + q3);
    __syncthreads();
    if (t < 64) {
        double S1 = red1[t] + red1[t + 64] + red1[t + 128] + red1[t + 192];
        double S2 = red2[t] + red2[t + 64] + red2[t + 128] + red2[t + 192];
        double mu = S1 / (double)N_;
        double var = S2 / (double)N_ - mu * mu;
        double scale = (double)gamma[t] / sqrt(var + (double)EPS_);
        double shift = (double)beta[t] - mu * scale;
        stats[t] = (float)scale;
        stats[64 + t] = (float)shift;
    }
}

// -------------- Kernel 4: sigmoid + per-batch-chunk partial pool -------------
__global__ __launch_bounds__(256) void pool_partial_kernel(const float* __restrict__ x,
                                                           const float* __restrict__ stats,
                                                           float* __restrict__ pp) {
    __shared__ float red[4][64];
    int blk = blockIdx.x;            // 32 batches * 32 chunks of 64 rows
    int b = blk >> 5, ch = blk & 31;
    int f = threadIdx.x & 63, w = threadIdx.x >> 6;
    float scale = stats[f], shift = stats[64 + f];
    float acc = 0.f;
    int row0 = b * P_ + ch * 64;
    for (int r = w; r < 64; r += 4) {
        float v = x[(size_t)(row0 + r) * 64 + f];
        float t = fmaf(v, scale, shift);
        acc += __fdividef(1.f, 1.f + __expf(-t));
    }
    red[w][f] = acc; __syncthreads();
    if (threadIdx.x < 64) pp[blk * 64 + f] = red[0][f] + red[1][f] + red[2][f] + red[3][f];
}

// ------------------ Kernel 5: batch means + GEMM1 + ELU ----------------------
__global__ __launch_bounds__(256) void mlp1_kernel(const float* __restrict__ pp,
                                                   const float* __restrict__ w1,
                                                   const float* __restrict__ b1,
                                                   float* __restrict__ y1) {
    __shared__ float ssy[64];
    int b = blockIdx.x, t = threadIdx.x;
    if (t < 64) {
        float s = 0.f;
#pragma unroll
        for (int g = 0; g < 32; g++) s += pp[(b * 32 + g) * 64 + t];
        ssy[t] = s * (1.f / 2048.f);
    }
    __syncthreads();
    float acc = b1[t];
#pragma unroll 8
    for (int c = 0; c < F_; c++) acc = fmaf(ssy[c], w1[c * 256 + t], acc);
    y1[b * 256 + t] = acc > 0.f ? acc : expm1f(acc);
}

// ------------------ Kernel 6: GEMM2 + log_softmax (wave-wide) ----------------
__global__ __launch_bounds__(64) void mlp2_kernel(const float* __restrict__ y1,
                                                  const float* __restrict__ w2,
                                                  const float* __restrict__ b2,
                                                  float* __restrict__ out) {
    int b = blockIdx.x, j = threadIdx.x;
    float acc = -INFINITY;
    if (j < NC_) {
        acc = b2[j];
#pragma unroll 8
        for (int c = 0; c < H_; c++) acc = fmaf(y1[b * 256 + c], w2[c * 40 + j], acc);
    }
    float m = acc;
#pragma unroll
    for (int o = 32; o > 0; o >>= 1) m = fmaxf(m, __shfl_xor(m, o, 64));
    float e = (j < NC_) ? expf(acc - m) : 0.f;
    float s = e;
#pragma unroll
    for (int o = 32; o > 0; o >>= 1) s += __shfl_xor(s, o, 64);
    if (j < NC_) out[b * NC_ + j] = acc - m - logf(s);
}

extern "C" void kernel_launch(void* const* d_in, const int* in_sizes, int n_in,
                              void* d_out, int out_size, void* d_ws, size_t ws_size,
                              hipStream_t stream) {
    const float* pos      = (const float*)d_in[0];
    const float* w_spline = (const float*)d_in[2];
    const float* w_root   = (const float*)d_in[3];
    const float* b_spline = (const float*)d_in[4];
    const float* bn_gamma = (const float*)d_in[5];
    const float* bn_beta  = (const float*)d_in[6];
    const float* w1       = (const float*)d_in[7];
    const float* b1       = (const float*)d_in[8];
    const float* w2       = (const float*)d_in[9];
    const float* b2       = (const float*)d_in[10];
    float* out = (float*)d_out;

    char* ws = (char*)d_ws;
    float* dcn      = (float*)(ws + 0);                    // 12 MB
    float* x        = (float*)(ws + (12u << 20));          // 16 MB
    float* partials = (float*)(ws + (28u << 20));          // 512 KB
    float* stats    = (float*)(ws + (28u << 20) + (512u << 10));               // 4 KB slot
    float* pp       = (float*)(ws + (28u << 20) + (512u << 10) + 4096);        // 256 KB
    float* y1       = (float*)(ws + (28u << 20) + (512u << 10) + 4096 + (256u << 10)); // 32 KB

    knn_geom_kernel<<<B_ * 32, 256, 0, stream>>>(pos, dcn);
    spline_kernel<<<N_ / 64, 256, 0, stream>>>(dcn, w_spline, w_root, b_spline, x, partials);
    stats_kernel<<<1, 256, 0, stream>>>(partials, bn_gamma, bn_beta, stats);
    pool_partial_kernel<<<B_ * 32, 256, 0, stream>>>(x, stats, pp);
    mlp1_kernel<<<B_, 256, 0, stream>>>(pp, w1, b1, y1);
    mlp2_kernel<<<B_, 64, 0, stream>>>(y1, w2, b2, out);
}

// Round 12
// 208.060 us; speedup vs baseline: 1.2357x; 1.0418x over previous
//
#include <hip/hip_runtime.h>
#include <math.h>

#define B_ 32
#define P_ 2048
#define N_ 65536
#define K_ 16
#define L_ 8
#define F_ 64
#define KS_ 5
#define KS3_ 125
#define NC_ 40
#define H_ 256
#define EPS_ 1e-5f
#define QPB_ 64      // queries per block
#define SEG_ 4       // segment lanes per query
#define SEGLEN_ 512  // candidates per segment lane

// exact same fp expression everywhere (pinned fmaf order)
__device__ __forceinline__ float distf(float4 C, float nx, float ny, float nz, float qs) {
    return fmaf(C.x, nx, fmaf(C.y, ny, fmaf(C.z, nz, C.w))) + qs;
}

// compare-exchange (ascending): 2 inst
#define CES(a, b) { unsigned _mn = min(a, b); b = max(a, b); a = _mn; }

// Batcher odd-even mergesort of 8 (19 CE)
__device__ __forceinline__ void sort8(unsigned& e0, unsigned& e1, unsigned& e2, unsigned& e3,
                                      unsigned& e4, unsigned& e5, unsigned& e6, unsigned& e7) {
    CES(e0, e1) CES(e2, e3) CES(e4, e5) CES(e6, e7)
    CES(e0, e2) CES(e1, e3) CES(e4, e6) CES(e5, e7)
    CES(e1, e2) CES(e5, e6)
    CES(e0, e4) CES(e1, e5) CES(e2, e6) CES(e3, e7)
    CES(e2, e4) CES(e3, e5)
    CES(e1, e2) CES(e3, e4) CES(e5, e6)
}

// ascending bitonic merge of a bitonic 16-sequence (32 CE, fully static)
__device__ __forceinline__ void bitmerge16(unsigned (&a)[16]) {
#pragma unroll
    for (int dd = 8; dd >= 1; dd >>= 1)
#pragma unroll
        for (int k2 = 0; k2 < 16; k2 += 2 * dd)
#pragma unroll
            for (int i2 = k2; i2 < k2 + dd; i2++)
                CES(a[i2], a[i2 + dd])
}

// full sort of 16 keys: sort8 halves, reverse hi (register renames), bitonic merge
__device__ __forceinline__ void sort16(unsigned (&a)[16]) {
    sort8(a[0], a[1], a[2], a[3], a[4], a[5], a[6], a[7]);
    sort8(a[8], a[9], a[10], a[11], a[12], a[13], a[14], a[15]);
    unsigned t;
    t = a[8];  a[8]  = a[15]; a[15] = t;
    t = a[9];  a[9]  = a[14]; a[14] = t;
    t = a[10]; a[10] = a[13]; a[13] = t;
    t = a[11]; a[11] = a[12]; a[12] = t;
    bitmerge16(a);
}

// Flush 8 buffered keys into sorted-ascending bu[16], Batcher-style:
// sort-8 + half-cleaner vs bu + bitonic merge == 8 sequential sorted-inserts
__device__ __forceinline__ void flush8(unsigned (&bu)[16],
                                       unsigned& e0, unsigned& e1, unsigned& e2, unsigned& e3,
                                       unsigned& e4, unsigned& e5, unsigned& e6, unsigned& e7,
                                       unsigned& thr) {
    sort8(e0, e1, e2, e3, e4, e5, e6, e7);
    CES(bu[8],  e7) CES(bu[9],  e6) CES(bu[10], e5) CES(bu[11], e4)
    CES(bu[12], e3) CES(bu[13], e2) CES(bu[14], e1) CES(bu[15], e0)
    bitmerge16(bu);
    e0 = e1 = e2 = e3 = e4 = e5 = e6 = e7 = 0xFFFFFFFFu;
    unsigned t16 = bu[15];          // share threshold across the 4 seg-lanes
    t16 = min(t16, (unsigned)__shfl_xor((int)t16, 1, 64));
    t16 = min(t16, (unsigned)__shfl_xor((int)t16, 2, 64));
    thr = min(thr, t16);
}

// ---- Kernel 1: KNN + geometry, 4 segment-lanes per query ----
// Block = 64 queries x 4 segments (256 thr). Lane: s = t&3, query = t>>2.
// WARM-START: the first 16 rotated candidates fill bu directly (sort16),
// thr initialized to the 4-lane min of bu[15] -> kills the dense early-accept
// phase (was ~110 flushes/wave, now ~30). NO self test in the hot loop:
// self's key (= il, since d=0 and real distance keys are >> 2048) is the
// guaranteed minimum of the owning lane's bu -> removed post-scan by a
// 16-cndmask shift. Scan: packed keys (21-bit dist prefix | 11-bit idx),
// rotated visit order (banks 4jj+8s disjoint), depth-8 accept buffer,
// flush check once per 4 visits (trigger >=5 buffered -> max 8, no overflow).
// Threshold stays a valid upper bound on the union 16th (any posted bu[15]
// is some lane's 16th-of-seen; keys unique -> strict < exact in key space).
// Merge: 2 bitonic rounds -> all 4 lanes hold sorted union-top-16. Neighbor
// ORDER = key order (trunc d, j): differs from exact (d, j) only within
// 2^-11 trunc-ties (rare 8th/9th cov-membership swaps; same approximation
// class as the union-in-key-space already measured at absmax 0.031).
// __launch_bounds__(256,4): VGPR cap 128 >= ~90 peak live -> no spill.
__global__ __launch_bounds__(256, 4) void knn_geom_kernel(const float* __restrict__ pos,
                                                          float* __restrict__ dcn) {
    __shared__ float4 cloud[P_];                 // 32 KB
    int b = blockIdx.x >> 5, tile = blockIdx.x & 31;
    int base = b * P_;
    int t = threadIdx.x;
    for (int j = t; j < P_; j += 256) {
        float x = pos[(base + j) * 3 + 0];
        float y = pos[(base + j) * 3 + 1];
        float z = pos[(base + j) * 3 + 2];
        cloud[j] = make_float4(x, y, z, x * x + y * y + z * z);
    }
    __syncthreads();

    int s = t & 3;                                // segment lane
    int il = tile * QPB_ + (t >> 2);              // this lane's query
    float4 Q = cloud[il];
    float nx = -2.f * Q.x, ny = -2.f * Q.y, nz = -2.f * Q.z, qs = Q.w;

    int j0 = s << 9, off = s << 1;                // rotation: banks 4jj+8s

    // ---- warm-start: first 16 rotated candidates -> sorted bu, fresh thr ----
    unsigned bu[16];
#pragma unroll
    for (int m = 0; m < 16; m++) {
        int j_ = j0 | ((m + off) & 511);
        float4 Cv = cloud[j_];
        float d_ = distf(Cv, nx, ny, nz, qs);
        bu[m] = (__float_as_uint(fmaxf(d_, 0.f)) & 0xFFFFF800u) | (unsigned)j_;
    }
    sort16(bu);
    unsigned thr;
    {
        unsigned t16 = bu[15];
        t16 = min(t16, (unsigned)__shfl_xor((int)t16, 1, 64));
        t16 = min(t16, (unsigned)__shfl_xor((int)t16, 2, 64));
        thr = t16;
    }

    unsigned e0 = ~0u, e1 = ~0u, e2 = ~0u, e3 = ~0u,
             e4 = ~0u, e5 = ~0u, e6 = ~0u, e7 = ~0u;

#define VISIT(Cv, JJ) {                                                          \
        int j_ = j0 | (((JJ) + off) & 511);                                      \
        float d_ = distf(Cv, nx, ny, nz, qs);                                    \
        unsigned key_ = (__float_as_uint(fmaxf(d_, 0.f)) & 0xFFFFF800u)          \
                        | (unsigned)j_;                                          \
        bool a_ = (key_ < thr);                                                  \
        e7 = a_ ? e6 : e7;  e6 = a_ ? e5 : e6;  e5 = a_ ? e4 : e5;               \
        e4 = a_ ? e3 : e4;  e3 = a_ ? e2 : e3;  e2 = a_ ? e1 : e2;               \
        e1 = a_ ? e0 : e1;  e0 = a_ ? key_ : e0;                                 \
    }

    float4 c0 = cloud[j0 | ((16 + off) & 511)];
    float4 c1 = cloud[j0 | ((17 + off) & 511)];
    float4 c2 = cloud[j0 | ((18 + off) & 511)];
    float4 c3 = cloud[j0 | ((19 + off) & 511)];
    for (int jj = 16; jj < SEGLEN_; jj += 4) {
        float4 n0 = cloud[j0 | ((jj + off + 4) & 511)];
        float4 n1 = cloud[j0 | ((jj + off + 5) & 511)];
        float4 n2 = cloud[j0 | ((jj + off + 6) & 511)];
        float4 n3 = cloud[j0 | ((jj + off + 7) & 511)];
        VISIT(c0, jj + 0)
        VISIT(c1, jj + 1)
        VISIT(c2, jj + 2)
        VISIT(c3, jj + 3)
        if (__any(e4 != 0xFFFFFFFFu))             // some lane buffered >= 5
            flush8(bu, e0, e1, e2, e3, e4, e5, e6, e7, thr);
        c0 = n0; c1 = n1; c2 = n2; c3 = n3;
    }
    flush8(bu, e0, e1, e2, e3, e4, e5, e6, e7, thr);   // drain (<= 4 left)
#undef VISIT

    // ---- self-removal: owner lane's bu[0] is self (key = il, the global
    // minimum); shift it out (16 cndmask, wave-uniform flow) ----
    {
        bool own = (s == (il >> 9));
#pragma unroll
        for (int m = 0; m < 15; m++) bu[m] = own ? bu[m + 1] : bu[m];
        bu[15] = own ? 0xFFFFFFFFu : bu[15];
    }

    // ---- 2 bitonic rounds: all 4 seg-lanes -> sorted union-top-16 ----
#pragma unroll
    for (int mask = 1; mask <= 2; mask <<= 1) {
        unsigned o[16];
#pragma unroll
        for (int i = 0; i < 16; i++)
            o[i] = (unsigned)__shfl_xor((int)bu[15 - i], mask, 64);  // partner reversed
#pragma unroll
        for (int i = 0; i < 16; i++) bu[i] = min(bu[i], o[i]);       // half-cleaner
        bitmerge16(bu);
    }

    // ---- neighbor indices straight from sorted keys ----
    int mi[16];
#pragma unroll
    for (int m = 0; m < 16; m++) mi[m] = bu[m] & 0x7FF;

    // ---- geometry: cov over L=8, 5x QR (LAPACK Householder), dc ----
    float px = Q.x, py = Q.y, pz = Q.z;
    float A[3][3];
    {
        float a00 = 0, a01 = 0, a02 = 0, a11 = 0, a12 = 0, a22 = 0;
#pragma unroll
        for (int l = 0; l < L_; l++) {
            float4 Cv = cloud[mi[l]];
            float ccx = Cv.x - px, ccy = Cv.y - py, ccz = Cv.z - pz;
            a00 += ccx * ccx; a01 += ccx * ccy; a02 += ccx * ccz;
            a11 += ccy * ccy; a12 += ccy * ccz; a22 += ccz * ccz;
        }
        A[0][0] = a00; A[0][1] = a01; A[0][2] = a02;
        A[1][0] = a01; A[1][1] = a11; A[1][2] = a12;
        A[2][0] = a02; A[2][1] = a12; A[2][2] = a22;
    }
    float Vt[3][3] = {{1.f, 0.f, 0.f}, {0.f, 1.f, 0.f}, {0.f, 0.f, 1.f}};

    for (int it = 0; it < 5; it++) {
        float M00 = A[0][0], M01 = A[0][1], M02 = A[0][2];
        float M10 = A[1][0], M11 = A[1][1], M12 = A[1][2];
        float M20 = A[2][0], M21 = A[2][1], M22 = A[2][2];
        float tau0 = 0.f, v1 = 0.f, v2 = 0.f;
        float xn2 = M10 * M10 + M20 * M20;
        if (xn2 != 0.f) {
            float beta = -copysignf(sqrtf(M00 * M00 + xn2), M00);
            tau0 = (beta - M00) / beta;
            float inv = 1.f / (M00 - beta);
            v1 = M10 * inv; v2 = M20 * inv;
            float sc;
            sc = tau0 * (M01 + v1 * M11 + v2 * M21); M01 -= sc; M11 -= v1 * sc; M21 -= v2 * sc;
            sc = tau0 * (M02 + v1 * M12 + v2 * M22); M02 -= sc; M12 -= v1 * sc; M22 -= v2 * sc;
            M00 = beta;
        }
        float tau1 = 0.f, u2 = 0.f;
        if (M21 != 0.f) {
            float beta1 = -copysignf(sqrtf(M11 * M11 + M21 * M21), M11);
            tau1 = (beta1 - M11) / beta1;
            u2 = M21 / (M11 - beta1);
            float sc = tau1 * (M12 + u2 * M22); M12 -= sc; M22 -= u2 * sc;
            M11 = beta1;
        }
        float h11 = 1.f - tau1, h12 = -tau1 * u2, h22 = 1.f - tau1 * u2 * u2;
        float Qm[3][3];
        Qm[0][0] = 1.f - tau0;
        Qm[1][0] = -v1 * tau0;
        Qm[2][0] = -v2 * tau0;
        float t1 = tau0 * (v1 * h11 + v2 * h12);
        Qm[0][1] = -t1;
        Qm[1][1] = h11 - v1 * t1;
        Qm[2][1] = h12 - v2 * t1;
        float t2 = tau0 * (v1 * h12 + v2 * h22);
        Qm[0][2] = -t2;
        Qm[1][2] = h12 - v1 * t2;
        Qm[2][2] = h22 - v2 * t2;
        A[0][0] = M00 * Qm[0][0] + M01 * Qm[1][0] + M02 * Qm[2][0];
        A[0][1] = M00 * Qm[0][1] + M01 * Qm[1][1] + M02 * Qm[2][1];
        A[0][2] = M00 * Qm[0][2] + M01 * Qm[1][2] + M02 * Qm[2][2];
        A[1][0] = M11 * Qm[1][0] + M12 * Qm[2][0];
        A[1][1] = M11 * Qm[1][1] + M12 * Qm[2][1];
        A[1][2] = M11 * Qm[1][2] + M12 * Qm[2][2];
        A[2][0] = M22 * Qm[2][0];
        A[2][1] = M22 * Qm[2][1];
        A[2][2] = M22 * Qm[2][2];
        float nv[3][3];
#pragma unroll
        for (int r = 0; r < 3; r++)
#pragma unroll
            for (int cc = 0; cc < 3; cc++)
                nv[r][cc] = Vt[r][0] * Qm[0][cc] + Vt[r][1] * Qm[1][cc] + Vt[r][2] * Qm[2][cc];
#pragma unroll
        for (int r = 0; r < 3; r++)
#pragma unroll
            for (int cc = 0; cc < 3; cc++) Vt[r][cc] = nv[r][cc];
    }

    // pass B: z-column sum + abs-max (recompute c from LDS)
    float s2 = 0.f, mx01 = 0.f, mx2 = 0.f;
#pragma unroll
    for (int k = 0; k < K_; k++) {
        float4 Cv = cloud[mi[k]];
        float ccx = Cv.x - px, ccy = Cv.y - py, ccz = Cv.z - pz;
        float d0 = ccx * Vt[0][0] + ccy * Vt[1][0] + ccz * Vt[2][0];
        float d1 = ccx * Vt[0][1] + ccy * Vt[1][1] + ccz * Vt[2][1];
        float d2 = ccx * Vt[0][2] + ccy * Vt[1][2] + ccz * Vt[2][2];
        s2 += d2;
        mx01 = fmaxf(mx01, fmaxf(fabsf(d0), fabsf(d1)));
        mx2  = fmaxf(mx2, fabsf(d2));
    }
    float sg = (s2 > 0.f) ? 1.f : ((s2 < 0.f) ? -1.f : 0.f);
    float mx = fmaxf(mx01, (sg == 0.f) ? 0.f : mx2);
    float hs = 0.5f / mx;

    // pass C: project, normalize, write; the 4 seg-lanes split the 4 groups
    {
        int i = base + il;
        float4* row = (float4*)(dcn + (size_t)i * 48);
        int g = s;
        float v[12];
#pragma unroll
        for (int kk = 0; kk < 4; kk++) {
            int k = g * 4 + kk;
            float4 Cv = cloud[mi[k]];
            float ccx = Cv.x - px, ccy = Cv.y - py, ccz = Cv.z - pz;
            float d0 = ccx * Vt[0][0] + ccy * Vt[1][0] + ccz * Vt[2][0];
            float d1 = ccx * Vt[0][1] + ccy * Vt[1][1] + ccz * Vt[2][1];
            float d2 = (ccx * Vt[0][2] + ccy * Vt[1][2] + ccz * Vt[2][2]) * sg;
            v[kk * 3 + 0] = d0 * hs + 0.5f;
            v[kk * 3 + 1] = d1 * hs + 0.5f;
            v[kk * 3 + 2] = d2 * hs + 0.5f;
        }
#pragma unroll
        for (int r = 0; r < 3; r++)
            row[g * 3 + r] = make_float4(v[r * 4 + 0], v[r * 4 + 1],
                                         v[r * 4 + 2], v[r * 4 + 3]);
    }
}

// ---------- Kernel 2: trilinear spline gather + out_nondir + BN partials -----
__global__ __launch_bounds__(256) void spline_kernel(const float* __restrict__ dcn,
                                                     const float* __restrict__ w_spline,
                                                     const float* __restrict__ w_root,
                                                     const float* __restrict__ b_spline,
                                                     float* __restrict__ x,
                                                     float* __restrict__ partials) {
    __shared__ float ws_t[F_ * KS3_];   // [f][cell], 32000 B
    __shared__ float red[4][64];
    {
        int f = threadIdx.x & 63;
        for (int c = threadIdx.x >> 6; c < KS3_; c += 4)
            ws_t[f * KS3_ + c] = w_spline[c * 64 + f];
    }
    __syncthreads();
    int wave = threadIdx.x >> 6, f = threadIdx.x & 63;
    const float* wbase = &ws_t[f * KS3_];
    float wr = w_root[f] + b_spline[f];
    float s1 = 0.f, s2 = 0.f;
    for (int p = 0; p < 16; p++) {
        int i = blockIdx.x * 64 + wave * 16 + p;
        const float4* row = (const float4*)(dcn + (size_t)i * 48);
        float pr[48];
#pragma unroll
        for (int m = 0; m < 12; m++) {
            float4 v = row[m];
            pr[m * 4 + 0] = v.x; pr[m * 4 + 1] = v.y;
            pr[m * 4 + 2] = v.z; pr[m * 4 + 3] = v.w;
        }
        float acc = 0.f;
#pragma unroll
        for (int k = 0; k < K_; k++) {
            float p0 = pr[k * 3 + 0] * 4.f;
            float p1 = pr[k * 3 + 1] * 4.f;
            float p2 = pr[k * 3 + 2] * 4.f;
            float i0 = fminf(fmaxf(floorf(p0), 0.f), 3.f);
            float i1 = fminf(fmaxf(floorf(p1), 0.f), 3.f);
            float i2 = fminf(fmaxf(floorf(p2), 0.f), 3.f);
            float f0 = p0 - i0, f1 = p1 - i1, f2 = p2 - i2;
            float g0 = 1.f - f0, g1 = 1.f - f1, g2 = 1.f - f2;
            int c = (int)fmaf(i2, 25.f, fmaf(i1, 5.f, i0));
            const float* wp = wbase + c;
            float a0 = wp[0],  a1 = wp[1];
            float b0 = wp[5],  b1v = wp[6];
            float c0 = wp[25], c1 = wp[26];
            float d0 = wp[30], d1 = wp[31];
            float wA = g1 * g2, wB = f1 * g2, wC = g1 * f2, wD = f1 * f2;
            acc = fmaf(wA, fmaf(f0, a1, g0 * a0), acc);
            acc = fmaf(wB, fmaf(f0, b1v, g0 * b0), acc);
            acc = fmaf(wC, fmaf(f0, c1, g0 * c0), acc);
            acc = fmaf(wD, fmaf(f0, d1, g0 * d0), acc);
        }
        float xv = acc * (1.f / 16.f) + wr;
        x[(size_t)i * 64 + f] = xv;
        s1 += xv; s2 += xv * xv;
    }
    red[wave][f] = s1; __syncthreads();
    if (threadIdx.x < 64)
        partials[blockIdx.x * 128 + f] = red[0][f] + red[1][f] + red[2][f] + red[3][f];
    __syncthreads();
    red[wave][f] = s2; __syncthreads();
    if (threadIdx.x < 64)
        partials[blockIdx.x * 128 + 64 + f] = red[0][f] + red[1][f] + red[2][f] + red[3][f];
}

// ----------------------- Kernel 3: BN stats finalize -------------------------
__global__ __launch_bounds__(256) void stats_kernel(const float* __restrict__ partials,
                                                    const float* __restrict__ gamma,
                                                    const float* __restrict__ beta,
                                                    float* __restrict__ stats) {
    __shared__ double red1[256], red2[256];
    int t = threadIdx.x;
    int f = t & 63, g = t >> 6;
    double a0 = 0, a1 = 0, a2 = 0, a3 = 0, q0 = 0, q1 = 0, q2 = 0, q3 = 0;
    for (int b2 = g; b2 < 1024; b2 += 16) {
        a0 += (double)partials[(b2     ) * 128 + f];
        q0 += (double)partials[(b2     ) * 128 + 64 + f];
        a1 += (double)partials[(b2 +  4) * 128 + f];
        q1 += (double)partials[(b2 +  4) * 128 + 64 + f];
        a2 += (double)partials[(b2 +  8) * 128 + f];
        q2 += (double)partials[(b2 +  8) * 128 + 64 + f];
        a3 += (double)partials[(b2 + 12) * 128 + f];
        q3 += (double)partials[(b2 + 12) * 128 + 64 + f];
    }
    red1[t] = (a0 + a1) + (a2 + a3);
    red2[t] = (q0 + q1) + (q2 + q3);
    __syncthreads();
    if (t < 64) {
        double S1 = red1[t] + red1[t + 64] + red1[t + 128] + red1[t + 192];
        double S2 = red2[t] + red2[t + 64] + red2[t + 128] + red2[t + 192];
        double mu = S1 / (double)N_;
        double var = S2 / (double)N_ - mu * mu;
        double scale = (double)gamma[t] / sqrt(var + (double)EPS_);
        double shift = (double)beta[t] - mu * scale;
        stats[t] = (float)scale;
        stats[64 + t] = (float)shift;
    }
}

// -------------- Kernel 4: sigmoid + per-batch-chunk partial pool -------------
__global__ __launch_bounds__(256) void pool_partial_kernel(const float* __restrict__ x,
                                                           const float* __restrict__ stats,
                                                           float* __restrict__ pp) {
    __shared__ float red[4][64];
    int blk = blockIdx.x;            // 32 batches * 32 chunks of 64 rows
    int b = blk >> 5, ch = blk & 31;
    int f = threadIdx.x & 63, w = threadIdx.x >> 6;
    float scale = stats[f], shift = stats[64 + f];
    float acc = 0.f;
    int row0 = b * P_ + ch * 64;
    for (int r = w; r < 64; r += 4) {
        float v = x[(size_t)(row0 + r) * 64 + f];
        float t = fmaf(v, scale, shift);
        acc += __fdividef(1.f, 1.f + __expf(-t));
    }
    red[w][f] = acc; __syncthreads();
    if (threadIdx.x < 64) pp[blk * 64 + f] = red[0][f] + red[1][f] + red[2][f] + red[3][f];
}

// ------------------ Kernel 5: batch means + GEMM1 + ELU ----------------------
__global__ __launch_bounds__(256) void mlp1_kernel(const float* __restrict__ pp,
                                                   const float* __restrict__ w1,
                                                   const float* __restrict__ b1,
                                                   float* __restrict__ y1) {
    __shared__ float ssy[64];
    int b = blockIdx.x, t = threadIdx.x;
    if (t < 64) {
        float s = 0.f;
#pragma unroll
        for (int g = 0; g < 32; g++) s += pp[(b * 32 + g) * 64 + t];
        ssy[t] = s * (1.f / 2048.f);
    }
    __syncthreads();
    float acc = b1[t];
#pragma unroll 8
    for (int c = 0; c < F_; c++) acc = fmaf(ssy[c], w1[c * 256 + t], acc);
    y1[b * 256 + t] = acc > 0.f ? acc : expm1f(acc);
}

// ------------------ Kernel 6: GEMM2 + log_softmax (wave-wide) ----------------
__global__ __launch_bounds__(64) void mlp2_kernel(const float* __restrict__ y1,
                                                  const float* __restrict__ w2,
                                                  const float* __restrict__ b2,
                                                  float* __restrict__ out) {
    int b = blockIdx.x, j = threadIdx.x;
    float acc = -INFINITY;
    if (j < NC_) {
        acc = b2[j];
#pragma unroll 8
        for (int c = 0; c < H_; c++) acc = fmaf(y1[b * 256 + c], w2[c * 40 + j], acc);
    }
    float m = acc;
#pragma unroll
    for (int o = 32; o > 0; o >>= 1) m = fmaxf(m, __shfl_xor(m, o, 64));
    float e = (j < NC_) ? expf(acc - m) : 0.f;
    float s = e;
#pragma unroll
    for (int o = 32; o > 0; o >>= 1) s += __shfl_xor(s, o, 64);
    if (j < NC_) out[b * NC_ + j] = acc - m - logf(s);
}

extern "C" void kernel_launch(void* const* d_in, const int* in_sizes, int n_in,
                              void* d_out, int out_size, void* d_ws, size_t ws_size,
                              hipStream_t stream) {
    const float* pos      = (const float*)d_in[0];
    const float* w_spline = (const float*)d_in[2];
    const float* w_root   = (const float*)d_in[3];
    const float* b_spline = (const float*)d_in[4];
    const float* bn_gamma = (const float*)d_in[5];
    const float* bn_beta  = (const float*)d_in[6];
    const float* w1       = (const float*)d_in[7];
    const float* b1       = (const float*)d_in[8];
    const float* w2       = (const float*)d_in[9];
    const float* b2       = (const float*)d_in[10];
    float* out = (float*)d_out;

    char* ws = (char*)d_ws;
    float* dcn      = (float*)(ws + 0);                    // 12 MB
    float* x        = (float*)(ws + (12u << 20));          // 16 MB
    float* partials = (float*)(ws + (28u << 20));          // 512 KB
    float* stats    = (float*)(ws + (28u << 20) + (512u << 10));               // 4 KB slot
    float* pp       = (float*)(ws + (28u << 20) + (512u << 10) + 4096);        // 256 KB
    float* y1       = (float*)(ws + (28u << 20) + (512u << 10) + 4096 + (256u << 10)); // 32 KB

    knn_geom_kernel<<<B_ * 32, 256, 0, stream>>>(pos, dcn);
    spline_kernel<<<N_ / 64, 256, 0, stream>>>(dcn, w_spline, w_root, b_spline, x, partials);
    stats_kernel<<<1, 256, 0, stream>>>(partials, bn_gamma, bn_beta, stats);
    pool_partial_kernel<<<B_ * 32, 256, 0, stream>>>(x, stats, pp);
    mlp1_kernel<<<B_, 256, 0, stream>>>(pp, w1, b1, y1);
    mlp2_kernel<<<B_, 64, 0, stream>>>(y1, w2, b2, out);
}

// Round 13
// 192.142 us; speedup vs baseline: 1.3381x; 1.0828x over previous
//
#include <hip/hip_runtime.h>
#include <math.h>

#define B_ 32
#define P_ 2048
#define N_ 65536
#define K_ 16
#define L_ 8
#define F_ 64
#define KS_ 5
#define KS3_ 125
#define NC_ 40
#define H_ 256
#define EPS_ 1e-5f
#define QPB_ 64      // queries per block
#define SEG_ 4       // segment lanes per query

// exact same fp expression everywhere (pinned fmaf order)
__device__ __forceinline__ float distf(float4 C, float nx, float ny, float nz, float qs) {
    return fmaf(C.x, nx, fmaf(C.y, ny, fmaf(C.z, nz, C.w))) + qs;
}

// compare-exchange (ascending): 2 inst
#define CES(a, b) { unsigned _mn = min(a, b); b = max(a, b); a = _mn; }

// Batcher odd-even mergesort of 8 (19 CE)
__device__ __forceinline__ void sort8(unsigned& e0, unsigned& e1, unsigned& e2, unsigned& e3,
                                      unsigned& e4, unsigned& e5, unsigned& e6, unsigned& e7) {
    CES(e0, e1) CES(e2, e3) CES(e4, e5) CES(e6, e7)
    CES(e0, e2) CES(e1, e3) CES(e4, e6) CES(e5, e7)
    CES(e1, e2) CES(e5, e6)
    CES(e0, e4) CES(e1, e5) CES(e2, e6) CES(e3, e7)
    CES(e2, e4) CES(e3, e5)
    CES(e1, e2) CES(e3, e4) CES(e5, e6)
}

// ascending bitonic merge of a bitonic 16-sequence (32 CE, fully static)
__device__ __forceinline__ void bitmerge16(unsigned (&a)[16]) {
#pragma unroll
    for (int dd = 8; dd >= 1; dd >>= 1)
#pragma unroll
        for (int k2 = 0; k2 < 16; k2 += 2 * dd)
#pragma unroll
            for (int i2 = k2; i2 < k2 + dd; i2++)
                CES(a[i2], a[i2 + dd])
}

// full sort of 16 keys
__device__ __forceinline__ void sort16(unsigned (&a)[16]) {
    sort8(a[0], a[1], a[2], a[3], a[4], a[5], a[6], a[7]);
    sort8(a[8], a[9], a[10], a[11], a[12], a[13], a[14], a[15]);
    unsigned t;
    t = a[8];  a[8]  = a[15]; a[15] = t;
    t = a[9];  a[9]  = a[14]; a[14] = t;
    t = a[10]; a[10] = a[13]; a[13] = t;
    t = a[11]; a[11] = a[12]; a[12] = t;
    bitmerge16(a);
}

// Flush 8 buffered keys into sorted-ascending bu[16] (== 8 sorted-inserts)
__device__ __forceinline__ void flush8(unsigned (&bu)[16],
                                       unsigned& e0, unsigned& e1, unsigned& e2, unsigned& e3,
                                       unsigned& e4, unsigned& e5, unsigned& e6, unsigned& e7,
                                       unsigned& thr) {
    sort8(e0, e1, e2, e3, e4, e5, e6, e7);
    CES(bu[8],  e7) CES(bu[9],  e6) CES(bu[10], e5) CES(bu[11], e4)
    CES(bu[12], e3) CES(bu[13], e2) CES(bu[14], e1) CES(bu[15], e0)
    bitmerge16(bu);
    e0 = e1 = e2 = e3 = e4 = e5 = e6 = e7 = 0xFFFFFFFFu;
    unsigned t16 = bu[15];          // share threshold across the 4 seg-lanes
    t16 = min(t16, (unsigned)__shfl_xor((int)t16, 1, 64));
    t16 = min(t16, (unsigned)__shfl_xor((int)t16, 2, 64));
    thr = min(thr, t16);
}

// ---- Kernel 1: KNN + geometry, 4 segment-lanes per query ----
// Block = 64 queries x 4 segments (256 thr). Lane: s = t&3, query = t>>2.
// LINEAR scan (no per-visit wrap arithmetic): lane s covers its segment as
//   warm [off, off+15] -> sorted bu + fresh thr (off = 2s)
//   main [off+16, off+503] linear (ds_read offsets fold to immediates)
//   epi  [off+504, 511] (8 uniform iters, accept predicated v<496-off;
//        reads spill into an initialized +8 LDS pad, masked off)
//   head [0, off) (6 uniform iters, accept predicated tau<off)
// -> each candidate visited exactly once. Bank stagger preserved: dword bank
// = (8s + 4v) mod 32, disjoint quads per wave. Depth-8 accept buffer,
// flush check every 4 visits (trigger >=5 -> max 8, no overflow; checks kept
// through epi/head). Threshold = 4-lane min of bu[15] at each flush (any
// lane's 16th-of-seen >= union 16th; keys unique -> strict < exact in key
// space). Self (key = il, the global min of the owning lane) removed by a
// post-scan shift. 2 bitonic rounds -> sorted union-top-16; neighbor order =
// key order (trunc d, j) as in round 12 (absmax 0.031 << 0.088).
// No mi[]/prefetch-pipeline arrays: bu[m]&0x7FF inlined (round-12 spill fix:
// WRITE_SIZE 28.7 MB -> expect ~12.3 MB).
__global__ __launch_bounds__(256, 4) void knn_geom_kernel(const float* __restrict__ pos,
                                                          float* __restrict__ dcn) {
    __shared__ float4 cloud[P_ + 8];             // 32 KB + pad
    int b = blockIdx.x >> 5, tile = blockIdx.x & 31;
    int base = b * P_;
    int t = threadIdx.x;
    for (int j = t; j < P_; j += 256) {
        float x = pos[(base + j) * 3 + 0];
        float y = pos[(base + j) * 3 + 1];
        float z = pos[(base + j) * 3 + 2];
        cloud[j] = make_float4(x, y, z, x * x + y * y + z * z);
    }
    if (t < 8) cloud[P_ + t] = make_float4(0.f, 0.f, 0.f, 1e30f);  // pad: huge d
    __syncthreads();

    int s = t & 3;                                // segment lane
    int il = tile * QPB_ + (t >> 2);              // this lane's query
    float4 Q = cloud[il];
    float nx = -2.f * Q.x, ny = -2.f * Q.y, nz = -2.f * Q.z, qs = Q.w;

    int j0 = s << 9, off = s << 1;

    // ---- warm-start: candidates [off, off+15] -> sorted bu, fresh thr ----
    unsigned bu[16];
#pragma unroll
    for (int m = 0; m < 16; m++) {
        int j_ = j0 + off + m;
        float4 Cv = cloud[j_];
        float d_ = distf(Cv, nx, ny, nz, qs);
        bu[m] = (__float_as_uint(fmaxf(d_, 0.f)) & 0xFFFFF800u) | (unsigned)j_;
    }
    sort16(bu);
    unsigned thr;
    {
        unsigned t16 = bu[15];
        t16 = min(t16, (unsigned)__shfl_xor((int)t16, 1, 64));
        t16 = min(t16, (unsigned)__shfl_xor((int)t16, 2, 64));
        thr = t16;
    }

    unsigned e0 = ~0u, e1 = ~0u, e2 = ~0u, e3 = ~0u,
             e4 = ~0u, e5 = ~0u, e6 = ~0u, e7 = ~0u;

#define VISITL(Cv, Jv) {                                                         \
        float d_ = distf(Cv, nx, ny, nz, qs);                                    \
        unsigned key_ = (__float_as_uint(fmaxf(d_, 0.f)) & 0xFFFFF800u)          \
                        | (unsigned)(Jv);                                        \
        bool a_ = (key_ < thr);                                                  \
        e7 = a_ ? e6 : e7;  e6 = a_ ? e5 : e6;  e5 = a_ ? e4 : e5;               \
        e4 = a_ ? e3 : e4;  e3 = a_ ? e2 : e3;  e2 = a_ ? e1 : e2;               \
        e1 = a_ ? e0 : e1;  e0 = a_ ? key_ : e0;                                 \
    }
#define VISITP(Cv, Jv, P) {                                                      \
        float d_ = distf(Cv, nx, ny, nz, qs);                                    \
        unsigned key_ = (__float_as_uint(fmaxf(d_, 0.f)) & 0xFFFFF800u)          \
                        | (unsigned)(Jv);                                        \
        bool a_ = (key_ < thr) && (P);                                           \
        e7 = a_ ? e6 : e7;  e6 = a_ ? e5 : e6;  e5 = a_ ? e4 : e5;               \
        e4 = a_ ? e3 : e4;  e3 = a_ ? e2 : e3;  e2 = a_ ? e1 : e2;               \
        e1 = a_ ? e0 : e1;  e0 = a_ ? key_ : e0;                                 \
    }

    // ---- main: 488 linear visits, jj in [off+16, off+503] ----
    const float4* cp = &cloud[j0 + off + 16];
    int jc = j0 + off + 16;
    for (int v = 0; v < 488; v += 4) {
        float4 a0 = cp[v + 0], a1 = cp[v + 1], a2 = cp[v + 2], a3 = cp[v + 3];
        VISITL(a0, jc + 0)
        VISITL(a1, jc + 1)
        VISITL(a2, jc + 2)
        VISITL(a3, jc + 3)
        jc += 4;
        if (__any(e4 != 0xFFFFFFFFu))
            flush8(bu, e0, e1, e2, e3, e4, e5, e6, e7, thr);
    }
    // ---- epilogue: v = 488..495, accept iff v < 496-off (pad reads masked) --
    {
        int vlim = 496 - off;
#pragma unroll
        for (int v = 488; v < 492; v++) {
            float4 a0 = cp[v];
            VISITP(a0, jc, v < vlim) jc++;
        }
        if (__any(e4 != 0xFFFFFFFFu))
            flush8(bu, e0, e1, e2, e3, e4, e5, e6, e7, thr);
#pragma unroll
        for (int v = 492; v < 496; v++) {
            float4 a0 = cp[v];
            VISITP(a0, jc, v < vlim) jc++;
        }
        if (__any(e4 != 0xFFFFFFFFu))
            flush8(bu, e0, e1, e2, e3, e4, e5, e6, e7, thr);
    }
    // ---- head tail: [0, off) ----
    {
#pragma unroll
        for (int u = 0; u < 4; u++) {
            float4 a0 = cloud[j0 + u];
            VISITP(a0, j0 + u, u < off)
        }
        if (__any(e4 != 0xFFFFFFFFu))
            flush8(bu, e0, e1, e2, e3, e4, e5, e6, e7, thr);
#pragma unroll
        for (int u = 4; u < 6; u++) {
            float4 a0 = cloud[j0 + u];
            VISITP(a0, j0 + u, u < off)
        }
    }
    flush8(bu, e0, e1, e2, e3, e4, e5, e6, e7, thr);   // drain
#undef VISITL
#undef VISITP

    // ---- self-removal: owner lane's bu[0] is self (global min key) ----
    {
        bool own = (s == (il >> 9));
#pragma unroll
        for (int m = 0; m < 15; m++) bu[m] = own ? bu[m + 1] : bu[m];
        bu[15] = own ? 0xFFFFFFFFu : bu[15];
    }

    // ---- 2 bitonic rounds: all 4 seg-lanes -> sorted union-top-16 ----
#pragma unroll
    for (int mask = 1; mask <= 2; mask <<= 1) {
        unsigned o[16];
#pragma unroll
        for (int i = 0; i < 16; i++)
            o[i] = (unsigned)__shfl_xor((int)bu[15 - i], mask, 64);  // partner reversed
#pragma unroll
        for (int i = 0; i < 16; i++) bu[i] = min(bu[i], o[i]);       // half-cleaner
        bitmerge16(bu);
    }

    // ---- geometry: cov over L=8, 5x QR (LAPACK Householder), dc ----
    // neighbor index = bu[m] & 0x7FF, inlined (no mi[] array -> no spill)
    float px = Q.x, py = Q.y, pz = Q.z;
    float A[3][3];
    {
        float a00 = 0, a01 = 0, a02 = 0, a11 = 0, a12 = 0, a22 = 0;
#pragma unroll
        for (int l = 0; l < L_; l++) {
            float4 Cv = cloud[bu[l] & 0x7FF];
            float ccx = Cv.x - px, ccy = Cv.y - py, ccz = Cv.z - pz;
            a00 += ccx * ccx; a01 += ccx * ccy; a02 += ccx * ccz;
            a11 += ccy * ccy; a12 += ccy * ccz; a22 += ccz * ccz;
        }
        A[0][0] = a00; A[0][1] = a01; A[0][2] = a02;
        A[1][0] = a01; A[1][1] = a11; A[1][2] = a12;
        A[2][0] = a02; A[2][1] = a12; A[2][2] = a22;
    }
    float Vt[3][3] = {{1.f, 0.f, 0.f}, {0.f, 1.f, 0.f}, {0.f, 0.f, 1.f}};

    for (int it = 0; it < 5; it++) {
        float M00 = A[0][0], M01 = A[0][1], M02 = A[0][2];
        float M10 = A[1][0], M11 = A[1][1], M12 = A[1][2];
        float M20 = A[2][0], M21 = A[2][1], M22 = A[2][2];
        float tau0 = 0.f, v1 = 0.f, v2 = 0.f;
        float xn2 = M10 * M10 + M20 * M20;
        if (xn2 != 0.f) {
            float beta = -copysignf(sqrtf(M00 * M00 + xn2), M00);
            tau0 = (beta - M00) / beta;
            float inv = 1.f / (M00 - beta);
            v1 = M10 * inv; v2 = M20 * inv;
            float sc;
            sc = tau0 * (M01 + v1 * M11 + v2 * M21); M01 -= sc; M11 -= v1 * sc; M21 -= v2 * sc;
            sc = tau0 * (M02 + v1 * M12 + v2 * M22); M02 -= sc; M12 -= v1 * sc; M22 -= v2 * sc;
            M00 = beta;
        }
        float tau1 = 0.f, u2 = 0.f;
        if (M21 != 0.f) {
            float beta1 = -copysignf(sqrtf(M11 * M11 + M21 * M21), M11);
            tau1 = (beta1 - M11) / beta1;
            u2 = M21 / (M11 - beta1);
            float sc = tau1 * (M12 + u2 * M22); M12 -= sc; M22 -= u2 * sc;
            M11 = beta1;
        }
        float h11 = 1.f - tau1, h12 = -tau1 * u2, h22 = 1.f - tau1 * u2 * u2;
        float Qm[3][3];
        Qm[0][0] = 1.f - tau0;
        Qm[1][0] = -v1 * tau0;
        Qm[2][0] = -v2 * tau0;
        float t1 = tau0 * (v1 * h11 + v2 * h12);
        Qm[0][1] = -t1;
        Qm[1][1] = h11 - v1 * t1;
        Qm[2][1] = h12 - v2 * t1;
        float t2 = tau0 * (v1 * h12 + v2 * h22);
        Qm[0][2] = -t2;
        Qm[1][2] = h12 - v1 * t2;
        Qm[2][2] = h22 - v2 * t2;
        A[0][0] = M00 * Qm[0][0] + M01 * Qm[1][0] + M02 * Qm[2][0];
        A[0][1] = M00 * Qm[0][1] + M01 * Qm[1][1] + M02 * Qm[2][1];
        A[0][2] = M00 * Qm[0][2] + M01 * Qm[1][2] + M02 * Qm[2][2];
        A[1][0] = M11 * Qm[1][0] + M12 * Qm[2][0];
        A[1][1] = M11 * Qm[1][1] + M12 * Qm[2][1];
        A[1][2] = M11 * Qm[1][2] + M12 * Qm[2][2];
        A[2][0] = M22 * Qm[2][0];
        A[2][1] = M22 * Qm[2][1];
        A[2][2] = M22 * Qm[2][2];
        float nv[3][3];
#pragma unroll
        for (int r = 0; r < 3; r++)
#pragma unroll
            for (int cc = 0; cc < 3; cc++)
                nv[r][cc] = Vt[r][0] * Qm[0][cc] + Vt[r][1] * Qm[1][cc] + Vt[r][2] * Qm[2][cc];
#pragma unroll
        for (int r = 0; r < 3; r++)
#pragma unroll
            for (int cc = 0; cc < 3; cc++) Vt[r][cc] = nv[r][cc];
    }

    // pass B: z-column sum + abs-max
    float s2 = 0.f, mx01 = 0.f, mx2 = 0.f;
#pragma unroll
    for (int k = 0; k < K_; k++) {
        float4 Cv = cloud[bu[k] & 0x7FF];
        float ccx = Cv.x - px, ccy = Cv.y - py, ccz = Cv.z - pz;
        float d0 = ccx * Vt[0][0] + ccy * Vt[1][0] + ccz * Vt[2][0];
        float d1 = ccx * Vt[0][1] + ccy * Vt[1][1] + ccz * Vt[2][1];
        float d2 = ccx * Vt[0][2] + ccy * Vt[1][2] + ccz * Vt[2][2];
        s2 += d2;
        mx01 = fmaxf(mx01, fmaxf(fabsf(d0), fabsf(d1)));
        mx2  = fmaxf(mx2, fabsf(d2));
    }
    float sg = (s2 > 0.f) ? 1.f : ((s2 < 0.f) ? -1.f : 0.f);
    float mx = fmaxf(mx01, (sg == 0.f) ? 0.f : mx2);
    float hs = 0.5f / mx;

    // pass C: project, normalize, write; the 4 seg-lanes split the 4 groups
    {
        int i = base + il;
        float4* row = (float4*)(dcn + (size_t)i * 48);
        int g = s;
        float4 Cv0 = cloud[bu[g * 4 + 0] & 0x7FF];
        float4 Cv1 = cloud[bu[g * 4 + 1] & 0x7FF];
        float4 Cv2 = cloud[bu[g * 4 + 2] & 0x7FF];
        float4 Cv3 = cloud[bu[g * 4 + 3] & 0x7FF];
        float x0 = Cv0.x - px, y0 = Cv0.y - py, z0 = Cv0.z - pz;
        float x1 = Cv1.x - px, y1 = Cv1.y - py, z1 = Cv1.z - pz;
        float x2 = Cv2.x - px, y2 = Cv2.y - py, z2 = Cv2.z - pz;
        float x3 = Cv3.x - px, y3 = Cv3.y - py, z3 = Cv3.z - pz;
        float p00 = (x0 * Vt[0][0] + y0 * Vt[1][0] + z0 * Vt[2][0]) * hs + 0.5f;
        float p01 = (x0 * Vt[0][1] + y0 * Vt[1][1] + z0 * Vt[2][1]) * hs + 0.5f;
        float p02 = (x0 * Vt[0][2] + y0 * Vt[1][2] + z0 * Vt[2][2]) * sg * hs + 0.5f;
        float p10 = (x1 * Vt[0][0] + y1 * Vt[1][0] + z1 * Vt[2][0]) * hs + 0.5f;
        float p11 = (x1 * Vt[0][1] + y1 * Vt[1][1] + z1 * Vt[2][1]) * hs + 0.5f;
        float p12 = (x1 * Vt[0][2] + y1 * Vt[1][2] + z1 * Vt[2][2]) * sg * hs + 0.5f;
        float p20 = (x2 * Vt[0][0] + y2 * Vt[1][0] + z2 * Vt[2][0]) * hs + 0.5f;
        float p21 = (x2 * Vt[0][1] + y2 * Vt[1][1] + z2 * Vt[2][1]) * hs + 0.5f;
        float p22 = (x2 * Vt[0][2] + y2 * Vt[1][2] + z2 * Vt[2][2]) * sg * hs + 0.5f;
        float p30 = (x3 * Vt[0][0] + y3 * Vt[1][0] + z3 * Vt[2][0]) * hs + 0.5f;
        float p31 = (x3 * Vt[0][1] + y3 * Vt[1][1] + z3 * Vt[2][1]) * hs + 0.5f;
        float p32 = (x3 * Vt[0][2] + y3 * Vt[1][2] + z3 * Vt[2][2]) * sg * hs + 0.5f;
        row[g * 3 + 0] = make_float4(p00, p01, p02, p10);
        row[g * 3 + 1] = make_float4(p11, p12, p20, p21);
        row[g * 3 + 2] = make_float4(p22, p30, p31, p32);
    }
}

// ---------- Kernel 2: trilinear spline gather + out_nondir + BN partials -----
__global__ __launch_bounds__(256) void spline_kernel(const float* __restrict__ dcn,
                                                     const float* __restrict__ w_spline,
                                                     const float* __restrict__ w_root,
                                                     const float* __restrict__ b_spline,
                                                     float* __restrict__ x,
                                                     float* __restrict__ partials) {
    __shared__ float ws_t[F_ * KS3_];   // [f][cell], 32000 B
    __shared__ float red[4][64];
    {
        int f = threadIdx.x & 63;
        for (int c = threadIdx.x >> 6; c < KS3_; c += 4)
            ws_t[f * KS3_ + c] = w_spline[c * 64 + f];
    }
    __syncthreads();
    int wave = threadIdx.x >> 6, f = threadIdx.x & 63;
    const float* wbase = &ws_t[f * KS3_];
    float wr = w_root[f] + b_spline[f];
    float s1 = 0.f, s2 = 0.f;
    for (int p = 0; p < 16; p++) {
        int i = blockIdx.x * 64 + wave * 16 + p;
        const float4* row = (const float4*)(dcn + (size_t)i * 48);
        float pr[48];
#pragma unroll
        for (int m = 0; m < 12; m++) {
            float4 v = row[m];
            pr[m * 4 + 0] = v.x; pr[m * 4 + 1] = v.y;
            pr[m * 4 + 2] = v.z; pr[m * 4 + 3] = v.w;
        }
        float acc = 0.f;
#pragma unroll
        for (int k = 0; k < K_; k++) {
            float p0 = pr[k * 3 + 0] * 4.f;
            float p1 = pr[k * 3 + 1] * 4.f;
            float p2 = pr[k * 3 + 2] * 4.f;
            float i0 = fminf(fmaxf(floorf(p0), 0.f), 3.f);
            float i1 = fminf(fmaxf(floorf(p1), 0.f), 3.f);
            float i2 = fminf(fmaxf(floorf(p2), 0.f), 3.f);
            float f0 = p0 - i0, f1 = p1 - i1, f2 = p2 - i2;
            float g0 = 1.f - f0, g1 = 1.f - f1, g2 = 1.f - f2;
            int c = (int)fmaf(i2, 25.f, fmaf(i1, 5.f, i0));
            const float* wp = wbase + c;
            float a0 = wp[0],  a1 = wp[1];
            float b0 = wp[5],  b1v = wp[6];
            float c0 = wp[25], c1 = wp[26];
            float d0 = wp[30], d1 = wp[31];
            float wA = g1 * g2, wB = f1 * g2, wC = g1 * f2, wD = f1 * f2;
            acc = fmaf(wA, fmaf(f0, a1, g0 * a0), acc);
            acc = fmaf(wB, fmaf(f0, b1v, g0 * b0), acc);
            acc = fmaf(wC, fmaf(f0, c1, g0 * c0), acc);
            acc = fmaf(wD, fmaf(f0, d1, g0 * d0), acc);
        }
        float xv = acc * (1.f / 16.f) + wr;
        x[(size_t)i * 64 + f] = xv;
        s1 += xv; s2 += xv * xv;
    }
    red[wave][f] = s1; __syncthreads();
    if (threadIdx.x < 64)
        partials[blockIdx.x * 128 + f] = red[0][f] + red[1][f] + red[2][f] + red[3][f];
    __syncthreads();
    red[wave][f] = s2; __syncthreads();
    if (threadIdx.x < 64)
        partials[blockIdx.x * 128 + 64 + f] = red[0][f] + red[1][f] + red[2][f] + red[3][f];
}

// ----------------------- Kernel 3: BN stats finalize -------------------------
__global__ __launch_bounds__(256) void stats_kernel(const float* __restrict__ partials,
                                                    const float* __restrict__ gamma,
                                                    const float* __restrict__ beta,
                                                    float* __restrict__ stats) {
    __shared__ double red1[256], red2[256];
    int t = threadIdx.x;
    int f = t & 63, g = t >> 6;
    double a0 = 0, a1 = 0, a2 = 0, a3 = 0, q0 = 0, q1 = 0, q2 = 0, q3 = 0;
    for (int b2 = g; b2 < 1024; b2 += 16) {
        a0 += (double)partials[(b2     ) * 128 + f];
        q0 += (double)partials[(b2     ) * 128 + 64 + f];
        a1 += (double)partials[(b2 +  4) * 128 + f];
        q1 += (double)partials[(b2 +  4) * 128 + 64 + f];
        a2 += (double)partials[(b2 +  8) * 128 + f];
        q2 += (double)partials[(b2 +  8) * 128 + 64 + f];
        a3 += (double)partials[(b2 + 12) * 128 + f];
        q3 += (double)partials[(b2 + 12) * 128 + 64 + f];
    }
    red1[t] = (a0 + a1) + (a2 + a3);
    red2[t] = (q0 + q1) + (q2 + q3);
    __syncthreads();
    if (t < 64) {
        double S1 = red1[t] + red1[t + 64] + red1[t + 128] + red1[t + 192];
        double S2 = red2[t] + red2[t + 64] + red2[t + 128] + red2[t + 192];
        double mu = S1 / (double)N_;
        double var = S2 / (double)N_ - mu * mu;
        double scale = (double)gamma[t] / sqrt(var + (double)EPS_);
        double shift = (double)beta[t] - mu * scale;
        stats[t] = (float)scale;
        stats[64 + t] = (float)shift;
    }
}

// -------------- Kernel 4: sigmoid + per-batch-chunk partial pool -------------
__global__ __launch_bounds__(256) void pool_partial_kernel(const float* __restrict__ x,
                                                           const float* __restrict__ stats,
                                                           float* __restrict__ pp) {
    __shared__ float red[4][64];
    int blk = blockIdx.x;            // 32 batches * 32 chunks of 64 rows
    int b = blk >> 5, ch = blk & 31;
    int f = threadIdx.x & 63, w = threadIdx.x >> 6;
    float scale = stats[f], shift = stats[64 + f];
    float acc = 0.f;
    int row0 = b * P_ + ch * 64;
    for (int r = w; r < 64; r += 4) {
        float v = x[(size_t)(row0 + r) * 64 + f];
        float t = fmaf(v, scale, shift);
        acc += __fdividef(1.f, 1.f + __expf(-t));
    }
    red[w][f] = acc; __syncthreads();
    if (threadIdx.x < 64) pp[blk * 64 + f] = red[0][f] + red[1][f] + red[2][f] + red[3][f];
}

// --------- Kernel 5: batch means + GEMM1 + ELU + GEMM2 + log_softmax --------
__global__ __launch_bounds__(256) void mlp_kernel(const float* __restrict__ pp,
                                                  const float* __restrict__ w1,
                                                  const float* __restrict__ b1,
                                                  const float* __restrict__ w2,
                                                  const float* __restrict__ b2,
                                                  float* __restrict__ out) {
    __shared__ float ssy[64];
    __shared__ float sy1[256];
    int b = blockIdx.x, t = threadIdx.x;
    if (t < 64) {
        float s = 0.f;
#pragma unroll
        for (int g = 0; g < 32; g++) s += pp[(b * 32 + g) * 64 + t];
        ssy[t] = s * (1.f / 2048.f);
    }
    __syncthreads();
    {
        float acc = b1[t];
#pragma unroll 8
        for (int c = 0; c < F_; c++) acc = fmaf(ssy[c], w1[c * 256 + t], acc);
        sy1[t] = acc > 0.f ? acc : expm1f(acc);
    }
    __syncthreads();
    if (t < 64) {
        int j = t;
        float acc = -INFINITY;
        if (j < NC_) {
            acc = b2[j];
#pragma unroll 8
            for (int c = 0; c < H_; c++) acc = fmaf(sy1[c], w2[c * 40 + j], acc);
        }
        float m = acc;
#pragma unroll
        for (int o = 32; o > 0; o >>= 1) m = fmaxf(m, __shfl_xor(m, o, 64));
        float e = (j < NC_) ? expf(acc - m) : 0.f;
        float s = e;
#pragma unroll
        for (int o = 32; o > 0; o >>= 1) s += __shfl_xor(s, o, 64);
        if (j < NC_) out[b * NC_ + j] = acc - m - logf(s);
    }
}

extern "C" void kernel_launch(void* const* d_in, const int* in_sizes, int n_in,
                              void* d_out, int out_size, void* d_ws, size_t ws_size,
                              hipStream_t stream) {
    const float* pos      = (const float*)d_in[0];
    const float* w_spline = (const float*)d_in[2];
    const float* w_root   = (const float*)d_in[3];
    const float* b_spline = (const float*)d_in[4];
    const float* bn_gamma = (const float*)d_in[5];
    const float* bn_beta  = (const float*)d_in[6];
    const float* w1       = (const float*)d_in[7];
    const float* b1       = (const float*)d_in[8];
    const float* w2       = (const float*)d_in[9];
    const float* b2       = (const float*)d_in[10];
    float* out = (float*)d_out;

    char* ws = (char*)d_ws;
    float* dcn      = (float*)(ws + 0);                    // 12 MB
    float* x        = (float*)(ws + (12u << 20));          // 16 MB
    float* partials = (float*)(ws + (28u << 20));          // 512 KB
    float* stats    = (float*)(ws + (28u << 20) + (512u << 10));               // 4 KB slot
    float* pp       = (float*)(ws + (28u << 20) + (512u << 10) + 4096);        // 256 KB

    knn_geom_kernel<<<B_ * 32, 256, 0, stream>>>(pos, dcn);
    spline_kernel<<<N_ / 64, 256, 0, stream>>>(dcn, w_spline, w_root, b_spline, x, partials);
    stats_kernel<<<1, 256, 0, stream>>>(partials, bn_gamma, bn_beta, stats);
    pool_partial_kernel<<<B_ * 32, 256, 0, stream>>>(x, stats, pp);
    mlp_kernel<<<B_, 256, 0, stream>>>(pp, w1, b1, w2, b2, out);
}